// Round 8
// baseline (456.284 us; speedup 1.0000x reference)
//
#include <hip/hip_runtime.h>
#include <math.h>

#define T_DIM  4096
#define REPR_D 2048
#define FEAT_D 1024
#define HID_D  1024
#define GATE_D 256
#define MH_D   256
#define NE     32
#define TOPK   4
#define ACT_D  12
#define LN_EPS 1e-5f

typedef unsigned short u16;
typedef __attribute__((ext_vector_type(8))) _Float16 f16x8;
typedef __attribute__((ext_vector_type(4))) float f32x4;
typedef __attribute__((ext_vector_type(4))) unsigned short u16x4;

__device__ __forceinline__ u16 f2h_bits(float f) {
  _Float16 h = (_Float16)f;
  return __builtin_bit_cast(u16, h);
}
__device__ __forceinline__ float h2f(u16 v) {
  return (float)__builtin_bit_cast(_Float16, v);
}
// split v = h0 + h1*2^-11, h1 stored pre-scaled by 2^11 (avoids fp16 subnormals)
__device__ __forceinline__ void split2h(float v, u16* h0, u16* h1) {
  _Float16 a = (_Float16)v;
  float r = v - (float)a;
  *h0 = __builtin_bit_cast(u16, a);
  *h1 = f2h_bits(r * 2048.0f);
}

__device__ __forceinline__ void gload16(const u16* g, u16* l) {
  __builtin_amdgcn_global_load_lds(
      (const __attribute__((address_space(1))) unsigned int*)g,
      (__attribute__((address_space(3))) unsigned int*)l, 16, 0, 0);
}

// ============ fp16x2 f32-emulated MFMA GEMM, BK=64, slot-XOR LDS swizzle ================
__global__ __launch_bounds__(256)
void gemm_f16x2_sk(const u16* __restrict__ A, const u16* __restrict__ Bt,
                   float* __restrict__ Cp, int M, int N, int K) {
  __shared__ u16 lA[2][128 * 64];
  __shared__ u16 lB[2][128 * 64];
  const int tid = threadIdx.x;
  const unsigned gx = gridDim.x, gy = gridDim.y;
  const unsigned lin = blockIdx.x + gx * (blockIdx.y + gy * blockIdx.z);
  const unsigned q = (gx * gy * gridDim.z) >> 3;
  const unsigned swz = (lin & 7) * q + (lin >> 3);
  const int bn = (swz % gx) * 128;
  const int bm = ((swz / gx) % gy) * 128;
  const int bz = swz / (gx * gy);
  const int ksl = K / gridDim.z;
  const int kbeg = bz * ksl, kend = kbeg + ksl;
  const int lane = tid & 63, wid = tid >> 6;
  const int wm = (wid >> 1) * 64, wn = (wid & 1) * 64;
  const size_t sA = (size_t)M * K, sB = (size_t)N * K;
  const int srow = tid >> 3;
  const int coff = (((tid & 7) ^ (srow & 7)) * 8);
  const u16* pa = A + (size_t)(bm + srow) * K + coff;
  const u16* pb = Bt + (size_t)(bn + srow) * K + coff;
  u16* la = &lA[0][0] + tid * 8;
  u16* lb = &lB[0][0] + tid * 8;
  const int fr = lane & 15;
  const int sx = lane >> 4;
  const int rx = lane & 7;
  f32x4 acc1[4][4] = {}, acc2[4][4] = {};
  for (int k0 = kbeg; k0 < kend; k0 += 64) {
    #pragma unroll
    for (int p = 0; p < 2; ++p)
      #pragma unroll
      for (int s = 0; s < 4; ++s) {
        gload16(pa + p * sA + (size_t)(s * 32) * K + k0, la + p * 8192 + s * 2048);
        gload16(pb + p * sB + (size_t)(s * 32) * K + k0, lb + p * 8192 + s * 2048);
      }
    __syncthreads();
    #pragma unroll
    for (int kh = 0; kh < 2; ++kh) {
      const int sa = (((kh << 2) | sx) ^ rx) * 8;
      f16x8 af0[4], af1[4], bq[4];
      #pragma unroll
      for (int m = 0; m < 4; ++m) {
        af0[m] = *(const f16x8*)&lA[0][(wm + m * 16 + fr) * 64 + sa];
        af1[m] = *(const f16x8*)&lA[1][(wm + m * 16 + fr) * 64 + sa];
      }
      #pragma unroll
      for (int n = 0; n < 4; ++n)
        bq[n] = *(const f16x8*)&lB[0][(wn + n * 16 + fr) * 64 + sa];
      #pragma unroll
      for (int m = 0; m < 4; ++m)
        #pragma unroll
        for (int n = 0; n < 4; ++n) {
          acc1[m][n] = __builtin_amdgcn_mfma_f32_16x16x32_f16(af0[m], bq[n], acc1[m][n], 0, 0, 0);
          acc2[m][n] = __builtin_amdgcn_mfma_f32_16x16x32_f16(af1[m], bq[n], acc2[m][n], 0, 0, 0);
        }
      #pragma unroll
      for (int n = 0; n < 4; ++n)
        bq[n] = *(const f16x8*)&lB[1][(wn + n * 16 + fr) * 64 + sa];
      #pragma unroll
      for (int m = 0; m < 4; ++m)
        #pragma unroll
        for (int n = 0; n < 4; ++n)
          acc2[m][n] = __builtin_amdgcn_mfma_f32_16x16x32_f16(af0[m], bq[n], acc2[m][n], 0, 0, 0);
    }
    __syncthreads();
  }
  float* Co = Cp + (size_t)bz * M * N;
  #pragma unroll
  for (int n = 0; n < 4; ++n) {
    const int col = bn + wn + n * 16 + (lane & 15);
    #pragma unroll
    for (int m = 0; m < 4; ++m) {
      #pragma unroll
      for (int r = 0; r < 4; ++r) {
        const int row = bm + wm + m * 16 + (lane >> 4) * 4 + r;
        Co[(size_t)row * N + col] = acc1[m][n][r] + acc2[m][n][r] * (1.0f / 2048.0f);
      }
    }
  }
}

// ============ expert layer 1: gathered-A fp16 MFMA, BK=64 + slot-XOR swizzle ===========
__global__ __launch_bounds__(256)
void expert_l1(const u16* __restrict__ x, const u16* __restrict__ ew1T,
               const float* __restrict__ eb1, const int* __restrict__ perm,
               const int* __restrict__ offsets, const int* __restrict__ counts,
               u16* __restrict__ hbuf) {
  const int e = blockIdx.z;
  const int cnt = counts[e];
  const int r0 = blockIdx.y * 128;
  if (r0 >= cnt) return;
  const int base = offsets[e];
  const int bn = blockIdx.x * 128;
  __shared__ u16 lA[128 * 64];
  __shared__ u16 lB[128 * 64];
  __shared__ int toksm[128];
  const int tid = threadIdx.x;
  if (tid < 128) toksm[tid] = (r0 + tid < cnt) ? (perm[base + r0 + tid] >> 2) : 0;
  __syncthreads();
  const int lane = tid & 63, wid = tid >> 6;
  const int wm = (wid >> 1) * 64, wn = (wid & 1) * 64;
  const int srow = tid >> 3;
  const int coff = ((tid & 7) ^ (srow & 7)) * 8;
  const u16* pa[4]; const u16* pb[4];
  #pragma unroll
  for (int s = 0; s < 4; ++s) {
    pa[s] = x + (size_t)toksm[srow + 32 * s] * HID_D + coff;
    pb[s] = ew1T + (size_t)e * MH_D * HID_D + (size_t)(bn + srow + 32 * s) * HID_D + coff;
  }
  u16* la = lA + tid * 8;
  u16* lb = lB + tid * 8;
  const int fr = lane & 15, sx = lane >> 4, rx = lane & 7;
  f32x4 acc[4][4] = {};
  for (int k0 = 0; k0 < HID_D; k0 += 64) {
    #pragma unroll
    for (int s = 0; s < 4; ++s) {
      gload16(pa[s] + k0, la + s * 2048);
      gload16(pb[s] + k0, lb + s * 2048);
    }
    __syncthreads();
    #pragma unroll
    for (int kh = 0; kh < 2; ++kh) {
      const int sa = (((kh << 2) | sx) ^ rx) * 8;
      f16x8 af[4], bfr[4];
      #pragma unroll
      for (int m = 0; m < 4; ++m)
        af[m] = *(const f16x8*)&lA[(wm + m * 16 + fr) * 64 + sa];
      #pragma unroll
      for (int n = 0; n < 4; ++n)
        bfr[n] = *(const f16x8*)&lB[(wn + n * 16 + fr) * 64 + sa];
      #pragma unroll
      for (int m = 0; m < 4; ++m)
        #pragma unroll
        for (int n = 0; n < 4; ++n)
          acc[m][n] = __builtin_amdgcn_mfma_f32_16x16x32_f16(af[m], bfr[n], acc[m][n], 0, 0, 0);
    }
    __syncthreads();
  }
  #pragma unroll
  for (int n = 0; n < 4; ++n) {
    const int col = bn + wn + n * 16 + (lane & 15);
    const float bz = eb1[e * MH_D + col];
    #pragma unroll
    for (int m = 0; m < 4; ++m) {
      #pragma unroll
      for (int r = 0; r < 4; ++r) {
        const int rl = wm + m * 16 + (lane >> 4) * 4 + r;
        if (r0 + rl < cnt) {
          const float v = fmaxf(acc[m][n][r] + bz, 0.f);
          hbuf[(size_t)(base + r0 + rl) * MH_D + col] = f2h_bits(v);
        }
      }
    }
  }
}

// ============ expert layer 2: fp16 MFMA, BK=64 + slot-XOR swizzle ======================
__global__ __launch_bounds__(256)
void expert_l2(const u16* __restrict__ hbuf, const u16* __restrict__ ew2T,
               const float* __restrict__ eb2, const int* __restrict__ offsets,
               const int* __restrict__ counts, u16* __restrict__ ybuf) {
  const int e = blockIdx.z;
  const int cnt = counts[e];
  const int r0 = blockIdx.y * 128;
  if (r0 >= cnt) return;
  const int base = offsets[e];
  const int bn = blockIdx.x * 128;
  __shared__ u16 lA[128 * 64];
  __shared__ u16 lB[128 * 64];
  const int tid = threadIdx.x;
  const int lane = tid & 63, wid = tid >> 6;
  const int wm = (wid >> 1) * 64, wn = (wid & 1) * 64;
  const int srow = tid >> 3;
  const int coff = ((tid & 7) ^ (srow & 7)) * 8;
  const u16* pa[4]; const u16* pb[4];
  #pragma unroll
  for (int s = 0; s < 4; ++s) {
    const int rr = r0 + srow + 32 * s;
    const int rc = (rr < cnt) ? rr : cnt - 1;
    pa[s] = hbuf + (size_t)(base + rc) * MH_D + coff;
    pb[s] = ew2T + (size_t)e * HID_D * MH_D + (size_t)(bn + srow + 32 * s) * MH_D + coff;
  }
  u16* la = lA + tid * 8;
  u16* lb = lB + tid * 8;
  const int fr = lane & 15, sx = lane >> 4, rx = lane & 7;
  f32x4 acc[4][4] = {};
  for (int k0 = 0; k0 < MH_D; k0 += 64) {
    #pragma unroll
    for (int s = 0; s < 4; ++s) {
      gload16(pa[s] + k0, la + s * 2048);
      gload16(pb[s] + k0, lb + s * 2048);
    }
    __syncthreads();
    #pragma unroll
    for (int kh = 0; kh < 2; ++kh) {
      const int sa = (((kh << 2) | sx) ^ rx) * 8;
      f16x8 af[4], bfr[4];
      #pragma unroll
      for (int m = 0; m < 4; ++m)
        af[m] = *(const f16x8*)&lA[(wm + m * 16 + fr) * 64 + sa];
      #pragma unroll
      for (int n = 0; n < 4; ++n)
        bfr[n] = *(const f16x8*)&lB[(wn + n * 16 + fr) * 64 + sa];
      #pragma unroll
      for (int m = 0; m < 4; ++m)
        #pragma unroll
        for (int n = 0; n < 4; ++n)
          acc[m][n] = __builtin_amdgcn_mfma_f32_16x16x32_f16(af[m], bfr[n], acc[m][n], 0, 0, 0);
    }
    __syncthreads();
  }
  #pragma unroll
  for (int n = 0; n < 4; ++n) {
    const int col = bn + wn + n * 16 + (lane & 15);
    const float bz = eb2[e * HID_D + col];
    #pragma unroll
    for (int m = 0; m < 4; ++m) {
      #pragma unroll
      for (int r = 0; r < 4; ++r) {
        const int rl = wm + m * 16 + (lane >> 4) * 4 + r;
        if (r0 + rl < cnt)
          ybuf[(size_t)(base + r0 + rl) * HID_D + col] = f2h_bits(acc[m][n][r] + bz);
      }
    }
  }
}

// ============ cast / transpose / split helpers ==========================================
__global__ __launch_bounds__(256)
void cast2h_k(const float* __restrict__ in, u16* __restrict__ out, size_t total) {
  const size_t i = ((size_t)blockIdx.x * 256 + threadIdx.x) * 4;
  const float4 v = *(const float4*)(in + i);
  const float vv[4] = {v.x, v.y, v.z, v.w};
  u16x4 o0, o1;
  #pragma unroll
  for (int j = 0; j < 4; ++j) {
    u16 a, b;
    split2h(vv[j], &a, &b);
    o0[j] = a; o1[j] = b;
  }
  *(u16x4*)(out + i) = o0;
  *(u16x4*)(out + total + i) = o1;
}

// in: f32 [K][N], out: 2 fp16 planes [N][K]
__global__ __launch_bounds__(256)
void transpose_cast2h(const float* __restrict__ in, u16* __restrict__ out, int K, int N) {
  __shared__ float t[32][33];
  const int bn = blockIdx.x * 32, bk = blockIdx.y * 32;
  const int tx = threadIdx.x & 31, ty = threadIdx.x >> 5;
  const size_t NK = (size_t)N * K;
  #pragma unroll
  for (int i = 0; i < 32; i += 8) t[ty + i][tx] = in[(size_t)(bk + ty + i) * N + bn + tx];
  __syncthreads();
  #pragma unroll
  for (int i = 0; i < 32; i += 8) {
    const size_t idx = (size_t)(bn + ty + i) * K + bk + tx;
    u16 h0, h1;
    split2h(t[tx][ty + i], &h0, &h1);
    out[idx] = h0; out[idx + NK] = h1;
  }
}

// single-plane fp16 transpose-cast (expert weights)
__global__ __launch_bounds__(256)
void transpose_casth(const float* __restrict__ in, u16* __restrict__ out, int K, int N) {
  const size_t off = (size_t)blockIdx.z * K * N;
  in += off; out += off;
  __shared__ float t[32][33];
  const int bn = blockIdx.x * 32, bk = blockIdx.y * 32;
  const int tx = threadIdx.x & 31, ty = threadIdx.x >> 5;
  #pragma unroll
  for (int i = 0; i < 32; i += 8) t[ty + i][tx] = in[(size_t)(bk + ty + i) * N + bn + tx];
  __syncthreads();
  #pragma unroll
  for (int i = 0; i < 32; i += 8) out[(size_t)(bn + ty + i) * K + bk + tx] = f2h_bits(t[tx][ty + i]);
}

// ============ LN + tanh: sums 2 trunk partials + bias -> 2 fp16 planes ==================
__global__ __launch_bounds__(256)
void ln_tanh2h(const float* __restrict__ hp, const float* __restrict__ tb,
               u16* __restrict__ outp, const float* __restrict__ g,
               const float* __restrict__ b) {
  const int row = blockIdx.x, tid = threadIdx.x;
  const size_t MN = (size_t)T_DIM * FEAT_D;
  const float4 va = ((const float4*)(hp + (size_t)row * FEAT_D))[tid];
  const float4 vb = ((const float4*)(hp + MN + (size_t)row * FEAT_D))[tid];
  const float4 vt = ((const float4*)tb)[tid];
  float4 v;
  v.x = va.x + vb.x + vt.x; v.y = va.y + vb.y + vt.y;
  v.z = va.z + vb.z + vt.z; v.w = va.w + vb.w + vt.w;
  float s = v.x + v.y + v.z + v.w;
  float ss = v.x * v.x + v.y * v.y + v.z * v.z + v.w * v.w;
  #pragma unroll
  for (int d = 32; d >= 1; d >>= 1) { s += __shfl_xor(s, d, 64); ss += __shfl_xor(ss, d, 64); }
  __shared__ float red[2][4];
  const int w = tid >> 6;
  if ((tid & 63) == 0) { red[0][w] = s; red[1][w] = ss; }
  __syncthreads();
  s  = red[0][0] + red[0][1] + red[0][2] + red[0][3];
  ss = red[1][0] + red[1][1] + red[1][2] + red[1][3];
  const float m = s * (1.f / FEAT_D);
  const float inv = rsqrtf(ss * (1.f / FEAT_D) - m * m + LN_EPS);
  const float4 gg = ((const float4*)g)[tid];
  const float4 bb = ((const float4*)b)[tid];
  const float tv[4] = {tanhf((v.x - m) * inv * gg.x + bb.x),
                       tanhf((v.y - m) * inv * gg.y + bb.y),
                       tanhf((v.z - m) * inv * gg.z + bb.z),
                       tanhf((v.w - m) * inv * gg.w + bb.w)};
  u16x4 o0, o1;
  #pragma unroll
  for (int j = 0; j < 4; ++j) {
    u16 a, c;
    split2h(tv[j], &a, &c);
    o0[j] = a; o1[j] = c;
  }
  ((u16x4*)(outp + (size_t)row * FEAT_D))[tid] = o0;
  ((u16x4*)(outp + MN + (size_t)row * FEAT_D))[tid] = o1;
}

// ============ p1 combiner: sum 2 partials + bias, relu, split2 ==========================
__global__ __launch_bounds__(256)
void combine2_relu_split2h(const float* __restrict__ P, const float* __restrict__ bias,
                           u16* __restrict__ out2) {
  const size_t MN = (size_t)T_DIM * HID_D;
  const size_t i = ((size_t)blockIdx.x * 256 + threadIdx.x) * 4;
  const float4 a = *(const float4*)(P + i);
  const float4 b = *(const float4*)(P + MN + i);
  const float4 bz = *(const float4*)(bias + (i & (HID_D - 1)));
  const float vv[4] = {fmaxf(a.x + b.x + bz.x, 0.f), fmaxf(a.y + b.y + bz.y, 0.f),
                       fmaxf(a.z + b.z + bz.z, 0.f), fmaxf(a.w + b.w + bz.w, 0.f)};
  u16x4 o0, o1;
  #pragma unroll
  for (int j = 0; j < 4; ++j) {
    u16 h0, h1;
    split2h(vv[j], &h0, &h1);
    o0[j] = h0; o1[j] = h1;
  }
  *(u16x4*)(out2 + i) = o0;
  *(u16x4*)(out2 + MN + i) = o1;
}

// ============ gate2: ILP logits + softmax + top-4 + renorm + aux =======================
__global__ __launch_bounds__(256)
void gate2_topk(const float* __restrict__ hgP, const float* __restrict__ g1b,
                const float* __restrict__ g2w, const float* __restrict__ g2b,
                float* __restrict__ imp, int* __restrict__ counts,
                int* __restrict__ topi, float* __restrict__ topw) {
  __shared__ float wsm[GATE_D][NE];
  __shared__ float rows[8][GATE_D];
  __shared__ float pacc[8][NE];
  const int tid = threadIdx.x;
  const int t0 = blockIdx.x * 8;
  const size_t TG = (size_t)T_DIM * GATE_D;
  {
    float4* wv = (float4*)&wsm[0][0];
    const float4* gv = (const float4*)g2w;
    #pragma unroll
    for (int i = 0; i < 8; ++i) wv[tid + 256 * i] = gv[tid + 256 * i];
  }
  {
    const float4* p0 = (const float4*)hgP;
    const float4* p1 = (const float4*)(hgP + TG);
    const float4* p2 = (const float4*)(hgP + 2 * TG);
    const float4* p3 = (const float4*)(hgP + 3 * TG);
    const float4* bv = (const float4*)g1b;
    float4* rv = (float4*)&rows[0][0];
    #pragma unroll
    for (int i = 0; i < 2; ++i) {
      const int idx = tid + 256 * i;
      const int r = idx >> 6, c4 = idx & 63;
      const size_t gidx = (size_t)(t0 + r) * (GATE_D / 4) + c4;
      const float4 a = p0[gidx], b = p1[gidx], c = p2[gidx], d = p3[gidx];
      const float4 bb = bv[c4];
      float4 v;
      v.x = fmaxf(a.x + b.x + c.x + d.x + bb.x, 0.f);
      v.y = fmaxf(a.y + b.y + c.y + d.y + bb.y, 0.f);
      v.z = fmaxf(a.z + b.z + c.z + d.z + bb.z, 0.f);
      v.w = fmaxf(a.w + b.w + c.w + d.w + bb.w, 0.f);
      rv[idx] = v;
    }
  }
  __syncthreads();
  const int tl = tid >> 5;
  const int e  = tid & 31;
  const int t  = t0 + tl;
  // 8 independent accumulator chains (depth 32) — latency-hiding ILP
  float a8[8] = {};
  #pragma unroll
  for (int k0 = 0; k0 < GATE_D; k0 += 8)
    #pragma unroll
    for (int j = 0; j < 8; ++j)
      a8[j] = fmaf(rows[tl][k0 + j], wsm[k0 + j][e], a8[j]);
  const float logit = g2b[e] +
      (((a8[0] + a8[1]) + (a8[2] + a8[3])) + ((a8[4] + a8[5]) + (a8[6] + a8[7])));
  float m = logit;
  #pragma unroll
  for (int d = 16; d >= 1; d >>= 1) m = fmaxf(m, __shfl_xor(m, d, 32));
  const float p = expf(logit - m);
  float ssum = p;
  #pragma unroll
  for (int d = 16; d >= 1; d >>= 1) ssum += __shfl_xor(ssum, d, 32);
  const float prob = p / ssum;
  pacc[tl][e] = prob;
  __syncthreads();
  if (tl == 0) {
    float a = 0.f;
    #pragma unroll
    for (int q = 0; q < 8; ++q) a += pacc[q][e];
    atomicAdd(&imp[e], a);
  }
  float cur = prob;
  float wv[TOPK]; int wi[TOPK];
  #pragma unroll
  for (int it = 0; it < TOPK; ++it) {
    float v = cur; int idx = e;
    #pragma unroll
    for (int d = 16; d >= 1; d >>= 1) {
      float v2 = __shfl_xor(v, d, 32);
      int   i2 = __shfl_xor(idx, d, 32);
      if (v2 > v || (v2 == v && i2 < idx)) { v = v2; idx = i2; }
    }
    wv[it] = v; wi[it] = idx;
    if (e == idx) cur = -1e30f;
  }
  if (e == 0) {
    const float s4 = wv[0] + wv[1] + wv[2] + wv[3];
    #pragma unroll
    for (int k2 = 0; k2 < TOPK; ++k2) {
      topi[t * TOPK + k2] = wi[k2];
      topw[t * TOPK + k2] = wv[k2] / s4;
      atomicAdd(&counts[wi[k2]], 1);
    }
  }
}

__global__ void scan_offsets(const int* __restrict__ counts, int* __restrict__ offsets) {
  if (threadIdx.x == 0) {
    int a = 0;
    for (int e = 0; e < NE; ++e) { offsets[e] = a; a += counts[e]; }
    offsets[NE] = a;
  }
}

__global__ __launch_bounds__(256)
void fill_perm(const int* __restrict__ topi, const int* __restrict__ offsets,
               int* __restrict__ fill, int* __restrict__ perm, int* __restrict__ inv) {
  const int s = blockIdx.x * 256 + threadIdx.x;
  const int e = topi[s];
  const int pos = atomicAdd(&fill[e], 1);
  perm[offsets[e] + pos] = s;
  inv[s] = offsets[e] + pos;
}

// ============ p2 head: gather 4 ybuf rows, combine, relu, GEMV, tanh; std ==============
__global__ __launch_bounds__(256)
void p2_head(const u16* __restrict__ ybuf, const int* __restrict__ inv,
             const float* __restrict__ topw, const float* __restrict__ w,
             const float* __restrict__ b, const float* __restrict__ stdp,
             float* __restrict__ outp) {
  const int t = (blockIdx.x * 256 + threadIdx.x) >> 6;
  const int lane = threadIdx.x & 63;
  if (t >= T_DIM) return;
  const int p0 = inv[t * 4 + 0], p1 = inv[t * 4 + 1];
  const int p2 = inv[t * 4 + 2], p3 = inv[t * 4 + 3];
  const float w0 = topw[t * 4 + 0], w1 = topw[t * 4 + 1];
  const float w2 = topw[t * 4 + 2], w3 = topw[t * 4 + 3];
  const u16* y0 = ybuf + (size_t)p0 * HID_D;
  const u16* y1 = ybuf + (size_t)p1 * HID_D;
  const u16* y2 = ybuf + (size_t)p2 * HID_D;
  const u16* y3 = ybuf + (size_t)p3 * HID_D;
  float a[ACT_D] = {};
  for (int k = lane; k < HID_D; k += 64) {
    float xv = w0 * h2f(y0[k]) + w1 * h2f(y1[k]) + w2 * h2f(y2[k]) + w3 * h2f(y3[k]);
    xv = fmaxf(xv, 0.f);
    const float* wr = w + (size_t)k * ACT_D;
    #pragma unroll
    for (int j = 0; j < ACT_D; ++j) a[j] = fmaf(xv, wr[j], a[j]);
  }
  #pragma unroll
  for (int j = 0; j < ACT_D; ++j) {
    float v = a[j];
    #pragma unroll
    for (int d = 32; d >= 1; d >>= 1) v += __shfl_xor(v, d, 64);
    a[j] = v;
  }
  if (lane == 0) {
    const float sv = stdp[0];
    #pragma unroll
    for (int j = 0; j < ACT_D; ++j) {
      outp[(size_t)t * ACT_D + j] = tanhf(a[j] + b[j]);
      outp[(size_t)T_DIM * ACT_D + (size_t)t * ACT_D + j] = sv;
    }
  }
}

__global__ void aux_kernel(const float* __restrict__ imp, const int* __restrict__ counts,
                           float* __restrict__ outp) {
  const int e = threadIdx.x;
  float v = 0.f;
  if (e < NE)
    v = (imp[e] / (float)T_DIM) * ((float)counts[e] / (float)(T_DIM * TOPK));
  #pragma unroll
  for (int d = 32; d >= 1; d >>= 1) v += __shfl_xor(v, d, 64);
  if (e == 0) outp[2 * T_DIM * ACT_D] = (float)NE * v;
}

extern "C" void kernel_launch(void* const* d_in, const int* in_sizes, int n_in,
                              void* d_out, int out_size, void* d_ws, size_t ws_size,
                              hipStream_t stream) {
  const float* obs     = (const float*)d_in[0];
  const float* stdp    = (const float*)d_in[1];
  const float* trunk_w = (const float*)d_in[2];
  const float* trunk_b = (const float*)d_in[3];
  const float* ln_g    = (const float*)d_in[4];
  const float* ln_b    = (const float*)d_in[5];
  const float* p1_w    = (const float*)d_in[6];
  const float* p1_b    = (const float*)d_in[7];
  const float* g1_w    = (const float*)d_in[8];
  const float* g1_b    = (const float*)d_in[9];
  const float* g2_w    = (const float*)d_in[10];
  const float* g2_b    = (const float*)d_in[11];
  const float* ew1     = (const float*)d_in[12];
  const float* eb1     = (const float*)d_in[13];
  const float* ew2     = (const float*)d_in[14];
  const float* eb2     = (const float*)d_in[15];
  const float* p2_w    = (const float*)d_in[16];
  const float* p2_b    = (const float*)d_in[17];
  float* out = (float*)d_out;

  // ---- workspace layout with lifetime overlays ----
  char* p = (char*)d_ws;
  // [A] 33.55 MB: obs2 -> {h2 16.78 | x2 16.78}; h2 -> hgP (4xTxGATE f32) after p1
  u16*   obs2 = (u16*)p;
  u16*   h2   = (u16*)p;
  float* hgP  = (float*)p;
  u16*   x2   = (u16*)(p + 2 * (size_t)T_DIM * FEAT_D * 2);
  p += 2 * (size_t)T_DIM * REPR_D * 2;
  // [B] 8.39 MB: trunk_wT2 -> {p1_wT2 4.19 + g1_wT2 1.05} -> hbuf 8.39
  u16* trunk_wT2 = (u16*)p;
  u16* p1_wT2    = (u16*)p;
  u16* g1_wT2    = (u16*)(p + 2 * (size_t)FEAT_D * HID_D * 2);
  u16* hbuf      = (u16*)p;
  p += 2 * (size_t)REPR_D * FEAT_D * 2;
  // [C] 33.55 MB: trunk partials (2 f32 planes) -> p1 partials -> ybuf (fp16, 16384x1024)
  float* hpP  = (float*)p;
  float* p1P  = (float*)p;
  u16*   ybuf = (u16*)p;
  p += 2 * (size_t)T_DIM * FEAT_D * 4;
  u16* ew1T = (u16*)p; p += (size_t)NE * HID_D * MH_D * 2;   // 16.78 MB
  u16* ew2T = (u16*)p; p += (size_t)NE * HID_D * MH_D * 2;   // 16.78 MB
  float* topw    = (float*)p; p += (size_t)T_DIM * TOPK * 4;
  int*   topi    = (int*)p;   p += (size_t)T_DIM * TOPK * 4;
  int*   perm    = (int*)p;   p += (size_t)T_DIM * TOPK * 4;
  int*   inv     = (int*)p;   p += (size_t)T_DIM * TOPK * 4;
  float* imp     = (float*)p; p += 128;
  int*   counts  = (int*)p;   p += 128;
  int*   offsets = (int*)p;   p += 256;
  int*   fill    = (int*)p;   p += 128;

  hipMemsetAsync(imp, 0, 128, stream);
  hipMemsetAsync(counts, 0, 128, stream);
  hipMemsetAsync(fill, 0, 128, stream);

  // obs + trunk_w -> 2-plane fp16 splits
  cast2h_k<<<(T_DIM * REPR_D) / 1024, 256, 0, stream>>>(obs, obs2, (size_t)T_DIM * REPR_D);
  transpose_cast2h<<<dim3(FEAT_D / 32, REPR_D / 32), 256, 0, stream>>>(trunk_w, trunk_wT2, REPR_D, FEAT_D);

  // trunk: 2-way split-K partials (512 blocks, XCD-chunked)
  gemm_f16x2_sk<<<dim3(FEAT_D / 128, T_DIM / 128, 2), 256, 0, stream>>>(
      obs2, trunk_wT2, hpP, T_DIM, FEAT_D, REPR_D);
  // [B] reuse (trunk_wT2 dead)
  transpose_cast2h<<<dim3(HID_D / 32, FEAT_D / 32), 256, 0, stream>>>(p1_w, p1_wT2, FEAT_D, HID_D);
  transpose_cast2h<<<dim3(GATE_D / 32, HID_D / 32), 256, 0, stream>>>(g1_w, g1_wT2, HID_D, GATE_D);

  // LN + tanh (sums 2 partials + bias) -> h2 ([A] reuse: obs2 dead)
  ln_tanh2h<<<T_DIM, 256, 0, stream>>>(hpP, trunk_b, h2, ln_g, ln_b);

  // p1: 2-way split-K partials ([C] reuse: hpP dead), then combine -> x2
  gemm_f16x2_sk<<<dim3(HID_D / 128, T_DIM / 128, 2), 256, 0, stream>>>(
      h2, p1_wT2, p1P, T_DIM, HID_D, FEAT_D);
  combine2_relu_split2h<<<(T_DIM * HID_D) / 1024, 256, 0, stream>>>(p1P, p1_b, x2);

  // gate1: 4-way split-K partials into hgP (h2 dead after p1)
  gemm_f16x2_sk<<<dim3(GATE_D / 128, T_DIM / 128, 4), 256, 0, stream>>>(
      x2, g1_wT2, hgP, T_DIM, GATE_D, HID_D);

  gate2_topk<<<T_DIM / 8, 256, 0, stream>>>(hgP, g1_b, g2_w, g2_b, imp, counts, topi, topw);
  scan_offsets<<<1, 64, 0, stream>>>(counts, offsets);
  fill_perm<<<(T_DIM * TOPK) / 256, 256, 0, stream>>>(topi, offsets, fill, perm, inv);

  // expert value path (fp16, plane0 of x2), weights fp16
  transpose_casth<<<dim3(MH_D / 32, HID_D / 32, NE), 256, 0, stream>>>(ew1, ew1T, HID_D, MH_D);
  transpose_casth<<<dim3(HID_D / 32, MH_D / 32, NE), 256, 0, stream>>>(ew2, ew2T, MH_D, HID_D);
  expert_l1<<<dim3(MH_D / 128, 32, NE), 256, 0, stream>>>(
      x2, ew1T, eb1, perm, offsets, counts, hbuf);
  // ybuf overlays p1P (dead after combine)
  expert_l2<<<dim3(HID_D / 128, 32, NE), 256, 0, stream>>>(
      hbuf, ew2T, eb2, offsets, counts, ybuf);

  p2_head<<<T_DIM / 4, 256, 0, stream>>>(ybuf, inv, topw, p2_w, p2_b, stdp, out);
  aux_kernel<<<1, 64, 0, stream>>>(imp, counts, out);
}

// Round 9
// 326.659 us; speedup vs baseline: 1.3968x; 1.3968x over previous
//
#include <hip/hip_runtime.h>
#include <math.h>

#define T_DIM  4096
#define REPR_D 2048
#define FEAT_D 1024
#define HID_D  1024
#define GATE_D 256
#define MH_D   256
#define NE     32
#define TOPK   4
#define ACT_D  12
#define LN_EPS 1e-5f
#define NB_G   (T_DIM / 8)     // gate2 blocks (8 tokens each)

typedef unsigned short u16;
typedef __attribute__((ext_vector_type(8))) _Float16 f16x8;
typedef __attribute__((ext_vector_type(4))) float f32x4;
typedef __attribute__((ext_vector_type(4))) unsigned short u16x4;

__device__ __forceinline__ u16 f2h_bits(float f) {
  _Float16 h = (_Float16)f;
  return __builtin_bit_cast(u16, h);
}
__device__ __forceinline__ float h2f(u16 v) {
  return (float)__builtin_bit_cast(_Float16, v);
}
// split v = h0 + h1*2^-11, h1 stored pre-scaled by 2^11 (avoids fp16 subnormals)
__device__ __forceinline__ void split2h(float v, u16* h0, u16* h1) {
  _Float16 a = (_Float16)v;
  float r = v - (float)a;
  *h0 = __builtin_bit_cast(u16, a);
  *h1 = f2h_bits(r * 2048.0f);
}

__device__ __forceinline__ void gload16(const u16* g, u16* l) {
  __builtin_amdgcn_global_load_lds(
      (const __attribute__((address_space(1))) unsigned int*)g,
      (__attribute__((address_space(3))) unsigned int*)l, 16, 0, 0);
}

// ============ fp16x2 f32-emulated MFMA GEMM, BK=64, slot-XOR LDS swizzle ================
__global__ __launch_bounds__(256)
void gemm_f16x2_sk(const u16* __restrict__ A, const u16* __restrict__ Bt,
                   float* __restrict__ Cp, int M, int N, int K) {
  __shared__ u16 lA[2][128 * 64];
  __shared__ u16 lB[2][128 * 64];
  const int tid = threadIdx.x;
  const unsigned gx = gridDim.x, gy = gridDim.y;
  const unsigned lin = blockIdx.x + gx * (blockIdx.y + gy * blockIdx.z);
  const unsigned q = (gx * gy * gridDim.z) >> 3;
  const unsigned swz = (lin & 7) * q + (lin >> 3);
  const int bn = (swz % gx) * 128;
  const int bm = ((swz / gx) % gy) * 128;
  const int bz = swz / (gx * gy);
  const int ksl = K / gridDim.z;
  const int kbeg = bz * ksl, kend = kbeg + ksl;
  const int lane = tid & 63, wid = tid >> 6;
  const int wm = (wid >> 1) * 64, wn = (wid & 1) * 64;
  const size_t sA = (size_t)M * K, sB = (size_t)N * K;
  const int srow = tid >> 3;
  const int coff = (((tid & 7) ^ (srow & 7)) * 8);
  const u16* pa = A + (size_t)(bm + srow) * K + coff;
  const u16* pb = Bt + (size_t)(bn + srow) * K + coff;
  u16* la = &lA[0][0] + tid * 8;
  u16* lb = &lB[0][0] + tid * 8;
  const int fr = lane & 15;
  const int sx = lane >> 4;
  const int rx = lane & 7;
  f32x4 acc1[4][4] = {}, acc2[4][4] = {};
  for (int k0 = kbeg; k0 < kend; k0 += 64) {
    #pragma unroll
    for (int p = 0; p < 2; ++p)
      #pragma unroll
      for (int s = 0; s < 4; ++s) {
        gload16(pa + p * sA + (size_t)(s * 32) * K + k0, la + p * 8192 + s * 2048);
        gload16(pb + p * sB + (size_t)(s * 32) * K + k0, lb + p * 8192 + s * 2048);
      }
    __syncthreads();
    #pragma unroll
    for (int kh = 0; kh < 2; ++kh) {
      const int sa = (((kh << 2) | sx) ^ rx) * 8;
      f16x8 af0[4], af1[4], bq[4];
      #pragma unroll
      for (int m = 0; m < 4; ++m) {
        af0[m] = *(const f16x8*)&lA[0][(wm + m * 16 + fr) * 64 + sa];
        af1[m] = *(const f16x8*)&lA[1][(wm + m * 16 + fr) * 64 + sa];
      }
      #pragma unroll
      for (int n = 0; n < 4; ++n)
        bq[n] = *(const f16x8*)&lB[0][(wn + n * 16 + fr) * 64 + sa];
      #pragma unroll
      for (int m = 0; m < 4; ++m)
        #pragma unroll
        for (int n = 0; n < 4; ++n) {
          acc1[m][n] = __builtin_amdgcn_mfma_f32_16x16x32_f16(af0[m], bq[n], acc1[m][n], 0, 0, 0);
          acc2[m][n] = __builtin_amdgcn_mfma_f32_16x16x32_f16(af1[m], bq[n], acc2[m][n], 0, 0, 0);
        }
      #pragma unroll
      for (int n = 0; n < 4; ++n)
        bq[n] = *(const f16x8*)&lB[1][(wn + n * 16 + fr) * 64 + sa];
      #pragma unroll
      for (int m = 0; m < 4; ++m)
        #pragma unroll
        for (int n = 0; n < 4; ++n)
          acc2[m][n] = __builtin_amdgcn_mfma_f32_16x16x32_f16(af0[m], bq[n], acc2[m][n], 0, 0, 0);
    }
    __syncthreads();
  }
  float* Co = Cp + (size_t)bz * M * N;
  #pragma unroll
  for (int n = 0; n < 4; ++n) {
    const int col = bn + wn + n * 16 + (lane & 15);
    #pragma unroll
    for (int m = 0; m < 4; ++m) {
      #pragma unroll
      for (int r = 0; r < 4; ++r) {
        const int row = bm + wm + m * 16 + (lane >> 4) * 4 + r;
        Co[(size_t)row * N + col] = acc1[m][n][r] + acc2[m][n][r] * (1.0f / 2048.0f);
      }
    }
  }
}

// ============ expert layer 1: gathered-A fp16 MFMA, BK=64 + slot-XOR swizzle ===========
__global__ __launch_bounds__(256)
void expert_l1(const u16* __restrict__ x, const u16* __restrict__ ew1T,
               const float* __restrict__ eb1, const int* __restrict__ perm,
               const int* __restrict__ offsets, const int* __restrict__ counts,
               u16* __restrict__ hbuf) {
  const int e = blockIdx.z;
  const int cnt = counts[e];
  const int r0 = blockIdx.y * 128;
  if (r0 >= cnt) return;
  const int base = offsets[e];
  const int bn = blockIdx.x * 128;
  __shared__ u16 lA[128 * 64];
  __shared__ u16 lB[128 * 64];
  __shared__ int toksm[128];
  const int tid = threadIdx.x;
  if (tid < 128) toksm[tid] = (r0 + tid < cnt) ? (perm[base + r0 + tid] >> 2) : 0;
  __syncthreads();
  const int lane = tid & 63, wid = tid >> 6;
  const int wm = (wid >> 1) * 64, wn = (wid & 1) * 64;
  const int srow = tid >> 3;
  const int coff = ((tid & 7) ^ (srow & 7)) * 8;
  const u16* pa[4]; const u16* pb[4];
  #pragma unroll
  for (int s = 0; s < 4; ++s) {
    pa[s] = x + (size_t)toksm[srow + 32 * s] * HID_D + coff;
    pb[s] = ew1T + (size_t)e * MH_D * HID_D + (size_t)(bn + srow + 32 * s) * HID_D + coff;
  }
  u16* la = lA + tid * 8;
  u16* lb = lB + tid * 8;
  const int fr = lane & 15, sx = lane >> 4, rx = lane & 7;
  f32x4 acc[4][4] = {};
  for (int k0 = 0; k0 < HID_D; k0 += 64) {
    #pragma unroll
    for (int s = 0; s < 4; ++s) {
      gload16(pa[s] + k0, la + s * 2048);
      gload16(pb[s] + k0, lb + s * 2048);
    }
    __syncthreads();
    #pragma unroll
    for (int kh = 0; kh < 2; ++kh) {
      const int sa = (((kh << 2) | sx) ^ rx) * 8;
      f16x8 af[4], bfr[4];
      #pragma unroll
      for (int m = 0; m < 4; ++m)
        af[m] = *(const f16x8*)&lA[(wm + m * 16 + fr) * 64 + sa];
      #pragma unroll
      for (int n = 0; n < 4; ++n)
        bfr[n] = *(const f16x8*)&lB[(wn + n * 16 + fr) * 64 + sa];
      #pragma unroll
      for (int m = 0; m < 4; ++m)
        #pragma unroll
        for (int n = 0; n < 4; ++n)
          acc[m][n] = __builtin_amdgcn_mfma_f32_16x16x32_f16(af[m], bfr[n], acc[m][n], 0, 0, 0);
    }
    __syncthreads();
  }
  #pragma unroll
  for (int n = 0; n < 4; ++n) {
    const int col = bn + wn + n * 16 + (lane & 15);
    const float bz = eb1[e * MH_D + col];
    #pragma unroll
    for (int m = 0; m < 4; ++m) {
      #pragma unroll
      for (int r = 0; r < 4; ++r) {
        const int rl = wm + m * 16 + (lane >> 4) * 4 + r;
        if (r0 + rl < cnt) {
          const float v = fmaxf(acc[m][n][r] + bz, 0.f);
          hbuf[(size_t)(base + r0 + rl) * MH_D + col] = f2h_bits(v);
        }
      }
    }
  }
}

// ============ expert layer 2: fp16 MFMA, BK=64 + slot-XOR swizzle ======================
__global__ __launch_bounds__(256)
void expert_l2(const u16* __restrict__ hbuf, const u16* __restrict__ ew2T,
               const float* __restrict__ eb2, const int* __restrict__ offsets,
               const int* __restrict__ counts, u16* __restrict__ ybuf) {
  const int e = blockIdx.z;
  const int cnt = counts[e];
  const int r0 = blockIdx.y * 128;
  if (r0 >= cnt) return;
  const int base = offsets[e];
  const int bn = blockIdx.x * 128;
  __shared__ u16 lA[128 * 64];
  __shared__ u16 lB[128 * 64];
  const int tid = threadIdx.x;
  const int lane = tid & 63, wid = tid >> 6;
  const int wm = (wid >> 1) * 64, wn = (wid & 1) * 64;
  const int srow = tid >> 3;
  const int coff = ((tid & 7) ^ (srow & 7)) * 8;
  const u16* pa[4]; const u16* pb[4];
  #pragma unroll
  for (int s = 0; s < 4; ++s) {
    const int rr = r0 + srow + 32 * s;
    const int rc = (rr < cnt) ? rr : cnt - 1;
    pa[s] = hbuf + (size_t)(base + rc) * MH_D + coff;
    pb[s] = ew2T + (size_t)e * HID_D * MH_D + (size_t)(bn + srow + 32 * s) * MH_D + coff;
  }
  u16* la = lA + tid * 8;
  u16* lb = lB + tid * 8;
  const int fr = lane & 15, sx = lane >> 4, rx = lane & 7;
  f32x4 acc[4][4] = {};
  for (int k0 = 0; k0 < MH_D; k0 += 64) {
    #pragma unroll
    for (int s = 0; s < 4; ++s) {
      gload16(pa[s] + k0, la + s * 2048);
      gload16(pb[s] + k0, lb + s * 2048);
    }
    __syncthreads();
    #pragma unroll
    for (int kh = 0; kh < 2; ++kh) {
      const int sa = (((kh << 2) | sx) ^ rx) * 8;
      f16x8 af[4], bfr[4];
      #pragma unroll
      for (int m = 0; m < 4; ++m)
        af[m] = *(const f16x8*)&lA[(wm + m * 16 + fr) * 64 + sa];
      #pragma unroll
      for (int n = 0; n < 4; ++n)
        bfr[n] = *(const f16x8*)&lB[(wn + n * 16 + fr) * 64 + sa];
      #pragma unroll
      for (int m = 0; m < 4; ++m)
        #pragma unroll
        for (int n = 0; n < 4; ++n)
          acc[m][n] = __builtin_amdgcn_mfma_f32_16x16x32_f16(af[m], bfr[n], acc[m][n], 0, 0, 0);
    }
    __syncthreads();
  }
  #pragma unroll
  for (int n = 0; n < 4; ++n) {
    const int col = bn + wn + n * 16 + (lane & 15);
    const float bz = eb2[e * HID_D + col];
    #pragma unroll
    for (int m = 0; m < 4; ++m) {
      #pragma unroll
      for (int r = 0; r < 4; ++r) {
        const int rl = wm + m * 16 + (lane >> 4) * 4 + r;
        if (r0 + rl < cnt)
          ybuf[(size_t)(base + r0 + rl) * HID_D + col] = f2h_bits(acc[m][n][r] + bz);
      }
    }
  }
}

// ============ cast / transpose / split helpers ==========================================
__global__ __launch_bounds__(256)
void cast2h_k(const float* __restrict__ in, u16* __restrict__ out, size_t total) {
  const size_t i = ((size_t)blockIdx.x * 256 + threadIdx.x) * 4;
  const float4 v = *(const float4*)(in + i);
  const float vv[4] = {v.x, v.y, v.z, v.w};
  u16x4 o0, o1;
  #pragma unroll
  for (int j = 0; j < 4; ++j) {
    u16 a, b;
    split2h(vv[j], &a, &b);
    o0[j] = a; o1[j] = b;
  }
  *(u16x4*)(out + i) = o0;
  *(u16x4*)(out + total + i) = o1;
}

// in: f32 [K][N], out: 2 fp16 planes [N][K]
__global__ __launch_bounds__(256)
void transpose_cast2h(const float* __restrict__ in, u16* __restrict__ out, int K, int N) {
  __shared__ float t[32][33];
  const int bn = blockIdx.x * 32, bk = blockIdx.y * 32;
  const int tx = threadIdx.x & 31, ty = threadIdx.x >> 5;
  const size_t NK = (size_t)N * K;
  #pragma unroll
  for (int i = 0; i < 32; i += 8) t[ty + i][tx] = in[(size_t)(bk + ty + i) * N + bn + tx];
  __syncthreads();
  #pragma unroll
  for (int i = 0; i < 32; i += 8) {
    const size_t idx = (size_t)(bn + ty + i) * K + bk + tx;
    u16 h0, h1;
    split2h(t[tx][ty + i], &h0, &h1);
    out[idx] = h0; out[idx + NK] = h1;
  }
}

// single-plane fp16 transpose-cast (expert weights)
__global__ __launch_bounds__(256)
void transpose_casth(const float* __restrict__ in, u16* __restrict__ out, int K, int N) {
  const size_t off = (size_t)blockIdx.z * K * N;
  in += off; out += off;
  __shared__ float t[32][33];
  const int bn = blockIdx.x * 32, bk = blockIdx.y * 32;
  const int tx = threadIdx.x & 31, ty = threadIdx.x >> 5;
  #pragma unroll
  for (int i = 0; i < 32; i += 8) t[ty + i][tx] = in[(size_t)(bk + ty + i) * N + bn + tx];
  __syncthreads();
  #pragma unroll
  for (int i = 0; i < 32; i += 8) out[(size_t)(bn + ty + i) * K + bk + tx] = f2h_bits(t[tx][ty + i]);
}

// ============ LN + tanh: sums 2 trunk partials + bias -> 2 fp16 planes ==================
__global__ __launch_bounds__(256)
void ln_tanh2h(const float* __restrict__ hp, const float* __restrict__ tb,
               u16* __restrict__ outp, const float* __restrict__ g,
               const float* __restrict__ b) {
  const int row = blockIdx.x, tid = threadIdx.x;
  const size_t MN = (size_t)T_DIM * FEAT_D;
  const float4 va = ((const float4*)(hp + (size_t)row * FEAT_D))[tid];
  const float4 vb = ((const float4*)(hp + MN + (size_t)row * FEAT_D))[tid];
  const float4 vt = ((const float4*)tb)[tid];
  float4 v;
  v.x = va.x + vb.x + vt.x; v.y = va.y + vb.y + vt.y;
  v.z = va.z + vb.z + vt.z; v.w = va.w + vb.w + vt.w;
  float s = v.x + v.y + v.z + v.w;
  float ss = v.x * v.x + v.y * v.y + v.z * v.z + v.w * v.w;
  #pragma unroll
  for (int d = 32; d >= 1; d >>= 1) { s += __shfl_xor(s, d, 64); ss += __shfl_xor(ss, d, 64); }
  __shared__ float red[2][4];
  const int w = tid >> 6;
  if ((tid & 63) == 0) { red[0][w] = s; red[1][w] = ss; }
  __syncthreads();
  s  = red[0][0] + red[0][1] + red[0][2] + red[0][3];
  ss = red[1][0] + red[1][1] + red[1][2] + red[1][3];
  const float m = s * (1.f / FEAT_D);
  const float inv = rsqrtf(ss * (1.f / FEAT_D) - m * m + LN_EPS);
  const float4 gg = ((const float4*)g)[tid];
  const float4 bb = ((const float4*)b)[tid];
  const float tv[4] = {tanhf((v.x - m) * inv * gg.x + bb.x),
                       tanhf((v.y - m) * inv * gg.y + bb.y),
                       tanhf((v.z - m) * inv * gg.z + bb.z),
                       tanhf((v.w - m) * inv * gg.w + bb.w)};
  u16x4 o0, o1;
  #pragma unroll
  for (int j = 0; j < 4; ++j) {
    u16 a, c;
    split2h(tv[j], &a, &c);
    o0[j] = a; o1[j] = c;
  }
  ((u16x4*)(outp + (size_t)row * FEAT_D))[tid] = o0;
  ((u16x4*)(outp + MN + (size_t)row * FEAT_D))[tid] = o1;
}

// ============ p1 combiner: sum 2 partials + bias, relu, split2 ==========================
__global__ __launch_bounds__(256)
void combine2_relu_split2h(const float* __restrict__ P, const float* __restrict__ bias,
                           u16* __restrict__ out2) {
  const size_t MN = (size_t)T_DIM * HID_D;
  const size_t i = ((size_t)blockIdx.x * 256 + threadIdx.x) * 4;
  const float4 a = *(const float4*)(P + i);
  const float4 b = *(const float4*)(P + MN + i);
  const float4 bz = *(const float4*)(bias + (i & (HID_D - 1)));
  const float vv[4] = {fmaxf(a.x + b.x + bz.x, 0.f), fmaxf(a.y + b.y + bz.y, 0.f),
                       fmaxf(a.z + b.z + bz.z, 0.f), fmaxf(a.w + b.w + bz.w, 0.f)};
  u16x4 o0, o1;
  #pragma unroll
  for (int j = 0; j < 4; ++j) {
    u16 h0, h1;
    split2h(vv[j], &h0, &h1);
    o0[j] = h0; o1[j] = h1;
  }
  *(u16x4*)(out2 + i) = o0;
  *(u16x4*)(out2 + MN + i) = o1;
}

// ============ gate2: logits + softmax + top-4 + per-block partials (NO global atomics) ==
__global__ __launch_bounds__(256)
void gate2_topk(const float* __restrict__ hgP, const float* __restrict__ g1b,
                const float* __restrict__ g2w, const float* __restrict__ g2b,
                float* __restrict__ blkimp, int* __restrict__ blkcnt,
                int* __restrict__ topi, float* __restrict__ topw,
                int* __restrict__ lrank) {
  __shared__ float wsm[GATE_D][NE];
  __shared__ float rows[8][GATE_D];
  __shared__ float pacc[8][NE];
  __shared__ int lhist[NE];
  const int tid = threadIdx.x;
  const int t0 = blockIdx.x * 8;
  const size_t TG = (size_t)T_DIM * GATE_D;
  if (tid < NE) lhist[tid] = 0;
  {
    float4* wv = (float4*)&wsm[0][0];
    const float4* gv = (const float4*)g2w;
    #pragma unroll
    for (int i = 0; i < 8; ++i) wv[tid + 256 * i] = gv[tid + 256 * i];
  }
  {
    const float4* p0 = (const float4*)hgP;
    const float4* p1 = (const float4*)(hgP + TG);
    const float4* p2 = (const float4*)(hgP + 2 * TG);
    const float4* p3 = (const float4*)(hgP + 3 * TG);
    const float4* bv = (const float4*)g1b;
    float4* rv = (float4*)&rows[0][0];
    #pragma unroll
    for (int i = 0; i < 2; ++i) {
      const int idx = tid + 256 * i;
      const int r = idx >> 6, c4 = idx & 63;
      const size_t gidx = (size_t)(t0 + r) * (GATE_D / 4) + c4;
      const float4 a = p0[gidx], b = p1[gidx], c = p2[gidx], d = p3[gidx];
      const float4 bb = bv[c4];
      float4 v;
      v.x = fmaxf(a.x + b.x + c.x + d.x + bb.x, 0.f);
      v.y = fmaxf(a.y + b.y + c.y + d.y + bb.y, 0.f);
      v.z = fmaxf(a.z + b.z + c.z + d.z + bb.z, 0.f);
      v.w = fmaxf(a.w + b.w + c.w + d.w + bb.w, 0.f);
      rv[idx] = v;
    }
  }
  __syncthreads();
  const int tl = tid >> 5;
  const int e  = tid & 31;
  const int t  = t0 + tl;
  float a8[8] = {};
  #pragma unroll
  for (int k0 = 0; k0 < GATE_D; k0 += 8)
    #pragma unroll
    for (int j = 0; j < 8; ++j)
      a8[j] = fmaf(rows[tl][k0 + j], wsm[k0 + j][e], a8[j]);
  const float logit = g2b[e] +
      (((a8[0] + a8[1]) + (a8[2] + a8[3])) + ((a8[4] + a8[5]) + (a8[6] + a8[7])));
  float m = logit;
  #pragma unroll
  for (int d = 16; d >= 1; d >>= 1) m = fmaxf(m, __shfl_xor(m, d, 32));
  const float p = expf(logit - m);
  float ssum = p;
  #pragma unroll
  for (int d = 16; d >= 1; d >>= 1) ssum += __shfl_xor(ssum, d, 32);
  const float prob = p / ssum;
  pacc[tl][e] = prob;
  __syncthreads();
  // per-block importance partials (plain store, reduced later)
  if (tl == 0) {
    float a = 0.f;
    #pragma unroll
    for (int q = 0; q < 8; ++q) a += pacc[q][e];
    blkimp[blockIdx.x * NE + e] = a;
  }
  // top-4 with tie-break to lower index
  float cur = prob;
  float wv[TOPK]; int wi[TOPK];
  #pragma unroll
  for (int it = 0; it < TOPK; ++it) {
    float v = cur; int idx = e;
    #pragma unroll
    for (int d = 16; d >= 1; d >>= 1) {
      float v2 = __shfl_xor(v, d, 32);
      int   i2 = __shfl_xor(idx, d, 32);
      if (v2 > v || (v2 == v && i2 < idx)) { v = v2; idx = i2; }
    }
    wv[it] = v; wi[it] = idx;
    if (e == idx) cur = -1e30f;
  }
  if (e == 0) {
    const float s4 = wv[0] + wv[1] + wv[2] + wv[3];
    #pragma unroll
    for (int k2 = 0; k2 < TOPK; ++k2) {
      topi[t * TOPK + k2] = wi[k2];
      topw[t * TOPK + k2] = wv[k2] / s4;
      lrank[t * TOPK + k2] = atomicAdd(&lhist[wi[k2]], 1);   // LDS atomic (per-CU, fast)
    }
  }
  __syncthreads();
  if (tid < NE) blkcnt[blockIdx.x * NE + tid] = lhist[tid];
}

// ============ scan: blkcnt -> counts, offsets, per-block bases (1 block) ================
__global__ __launch_bounds__(256)
void scan_k(const int* __restrict__ blkcnt, int* __restrict__ counts,
            int* __restrict__ offsets, int* __restrict__ blkbase) {
  __shared__ int segsum[8][NE];
  __shared__ int soff[8][NE];
  const int e = threadIdx.x & 31, seg = threadIdx.x >> 5;    // 8 segs x 64 blocks
  const int b0 = seg * 64;
  int vals[64];
  #pragma unroll
  for (int i = 0; i < 64; ++i) vals[i] = blkcnt[(b0 + i) * NE + e];
  int run = 0;
  #pragma unroll
  for (int i = 0; i < 64; ++i) { const int c = vals[i]; vals[i] = run; run += c; }
  segsum[seg][e] = run;
  __syncthreads();
  if (seg == 0) {
    int acc = 0;
    #pragma unroll
    for (int s2 = 0; s2 < 8; ++s2) { soff[s2][e] = acc; acc += segsum[s2][e]; }
    counts[e] = acc;
  }
  __syncthreads();
  if (threadIdx.x == 0) {
    int a = 0;
    for (int i = 0; i < NE; ++i) { offsets[i] = a; a += counts[i]; }
    offsets[NE] = a;
  }
  const int sb = soff[seg][e];
  #pragma unroll
  for (int i = 0; i < 64; ++i) blkbase[(b0 + i) * NE + e] = sb + vals[i];
}

// ============ fill_perm2: position = offsets + blkbase + lrank (NO atomics) =============
__global__ __launch_bounds__(256)
void fill_perm2(const int* __restrict__ topi, const int* __restrict__ lrank,
                const int* __restrict__ blkbase, const int* __restrict__ offsets,
                int* __restrict__ perm, int* __restrict__ inv) {
  const int s = blockIdx.x * 256 + threadIdx.x;
  const int e = topi[s];
  const int b = s >> 5;                       // 32 slots per gate2 block
  const int pos = offsets[e] + blkbase[b * NE + e] + lrank[s];
  perm[pos] = s;
  inv[s] = pos;
}

// ============ p2 head: gather 4 ybuf rows, combine, relu, GEMV, tanh; std ==============
__global__ __launch_bounds__(256)
void p2_head(const u16* __restrict__ ybuf, const int* __restrict__ inv,
             const float* __restrict__ topw, const float* __restrict__ w,
             const float* __restrict__ b, const float* __restrict__ stdp,
             float* __restrict__ outp) {
  const int t = (blockIdx.x * 256 + threadIdx.x) >> 6;
  const int lane = threadIdx.x & 63;
  if (t >= T_DIM) return;
  const int p0 = inv[t * 4 + 0], p1 = inv[t * 4 + 1];
  const int p2 = inv[t * 4 + 2], p3 = inv[t * 4 + 3];
  const float w0 = topw[t * 4 + 0], w1 = topw[t * 4 + 1];
  const float w2 = topw[t * 4 + 2], w3 = topw[t * 4 + 3];
  const u16* y0 = ybuf + (size_t)p0 * HID_D;
  const u16* y1 = ybuf + (size_t)p1 * HID_D;
  const u16* y2 = ybuf + (size_t)p2 * HID_D;
  const u16* y3 = ybuf + (size_t)p3 * HID_D;
  float a[ACT_D] = {};
  for (int k = lane; k < HID_D; k += 64) {
    float xv = w0 * h2f(y0[k]) + w1 * h2f(y1[k]) + w2 * h2f(y2[k]) + w3 * h2f(y3[k]);
    xv = fmaxf(xv, 0.f);
    const float* wr = w + (size_t)k * ACT_D;
    #pragma unroll
    for (int j = 0; j < ACT_D; ++j) a[j] = fmaf(xv, wr[j], a[j]);
  }
  #pragma unroll
  for (int j = 0; j < ACT_D; ++j) {
    float v = a[j];
    #pragma unroll
    for (int d = 32; d >= 1; d >>= 1) v += __shfl_xor(v, d, 64);
    a[j] = v;
  }
  if (lane == 0) {
    const float sv = stdp[0];
    #pragma unroll
    for (int j = 0; j < ACT_D; ++j) {
      outp[(size_t)t * ACT_D + j] = tanhf(a[j] + b[j]);
      outp[(size_t)T_DIM * ACT_D + (size_t)t * ACT_D + j] = sv;
    }
  }
}

// ============ aux: reduce blkimp deterministically + counts -> aux loss ================
__global__ __launch_bounds__(256)
void aux_kernel(const float* __restrict__ blkimp, const int* __restrict__ counts,
                float* __restrict__ outp) {
  __shared__ float part[8][NE];
  const int e = threadIdx.x & 31, seg = threadIdx.x >> 5;
  float a = 0.f;
  #pragma unroll
  for (int i = 0; i < 64; ++i) a += blkimp[((seg << 6) + i) * NE + e];
  part[seg][e] = a;
  __syncthreads();
  if (threadIdx.x < 32) {
    float impe = 0.f;
    #pragma unroll
    for (int s2 = 0; s2 < 8; ++s2) impe += part[s2][e];
    float v = (impe / (float)T_DIM) * ((float)counts[e] / (float)(T_DIM * TOPK));
    #pragma unroll
    for (int d = 16; d >= 1; d >>= 1) v += __shfl_xor(v, d, 32);
    if (e == 0) outp[2 * T_DIM * ACT_D] = (float)NE * v;
  }
}

extern "C" void kernel_launch(void* const* d_in, const int* in_sizes, int n_in,
                              void* d_out, int out_size, void* d_ws, size_t ws_size,
                              hipStream_t stream) {
  const float* obs     = (const float*)d_in[0];
  const float* stdp    = (const float*)d_in[1];
  const float* trunk_w = (const float*)d_in[2];
  const float* trunk_b = (const float*)d_in[3];
  const float* ln_g    = (const float*)d_in[4];
  const float* ln_b    = (const float*)d_in[5];
  const float* p1_w    = (const float*)d_in[6];
  const float* p1_b    = (const float*)d_in[7];
  const float* g1_w    = (const float*)d_in[8];
  const float* g1_b    = (const float*)d_in[9];
  const float* g2_w    = (const float*)d_in[10];
  const float* g2_b    = (const float*)d_in[11];
  const float* ew1     = (const float*)d_in[12];
  const float* eb1     = (const float*)d_in[13];
  const float* ew2     = (const float*)d_in[14];
  const float* eb2     = (const float*)d_in[15];
  const float* p2_w    = (const float*)d_in[16];
  const float* p2_b    = (const float*)d_in[17];
  float* out = (float*)d_out;

  // ---- workspace layout with lifetime overlays ----
  char* p = (char*)d_ws;
  // [A] 33.55 MB: obs2 -> {h2 16.78 | x2 16.78}; h2 -> hgP (4xTxGATE f32) after p1
  u16*   obs2 = (u16*)p;
  u16*   h2   = (u16*)p;
  float* hgP  = (float*)p;
  u16*   x2   = (u16*)(p + 2 * (size_t)T_DIM * FEAT_D * 2);
  p += 2 * (size_t)T_DIM * REPR_D * 2;
  // [B] 8.39 MB: trunk_wT2 -> {p1_wT2 4.19 + g1_wT2 1.05} -> hbuf 8.39
  u16* trunk_wT2 = (u16*)p;
  u16* p1_wT2    = (u16*)p;
  u16* g1_wT2    = (u16*)(p + 2 * (size_t)FEAT_D * HID_D * 2);
  u16* hbuf      = (u16*)p;
  p += 2 * (size_t)REPR_D * FEAT_D * 2;
  // [C] 33.55 MB: trunk partials (2 f32 planes) -> p1 partials -> ybuf (fp16, 16384x1024)
  float* hpP  = (float*)p;
  float* p1P  = (float*)p;
  u16*   ybuf = (u16*)p;
  p += 2 * (size_t)T_DIM * FEAT_D * 4;
  u16* ew1T = (u16*)p; p += (size_t)NE * HID_D * MH_D * 2;   // 16.78 MB
  u16* ew2T = (u16*)p; p += (size_t)NE * HID_D * MH_D * 2;   // 16.78 MB
  float* topw    = (float*)p; p += (size_t)T_DIM * TOPK * 4;
  int*   topi    = (int*)p;   p += (size_t)T_DIM * TOPK * 4;
  int*   perm    = (int*)p;   p += (size_t)T_DIM * TOPK * 4;
  int*   inv     = (int*)p;   p += (size_t)T_DIM * TOPK * 4;
  int*   lrank   = (int*)p;   p += (size_t)T_DIM * TOPK * 4;
  float* blkimp  = (float*)p; p += (size_t)NB_G * NE * 4;
  int*   blkcnt  = (int*)p;   p += (size_t)NB_G * NE * 4;
  int*   blkbase = (int*)p;   p += (size_t)NB_G * NE * 4;
  int*   counts  = (int*)p;   p += 128;
  int*   offsets = (int*)p;   p += 256;

  // obs + trunk_w -> 2-plane fp16 splits
  cast2h_k<<<(T_DIM * REPR_D) / 1024, 256, 0, stream>>>(obs, obs2, (size_t)T_DIM * REPR_D);
  transpose_cast2h<<<dim3(FEAT_D / 32, REPR_D / 32), 256, 0, stream>>>(trunk_w, trunk_wT2, REPR_D, FEAT_D);

  // trunk: 2-way split-K partials (512 blocks, XCD-chunked)
  gemm_f16x2_sk<<<dim3(FEAT_D / 128, T_DIM / 128, 2), 256, 0, stream>>>(
      obs2, trunk_wT2, hpP, T_DIM, FEAT_D, REPR_D);
  // [B] reuse (trunk_wT2 dead)
  transpose_cast2h<<<dim3(HID_D / 32, FEAT_D / 32), 256, 0, stream>>>(p1_w, p1_wT2, FEAT_D, HID_D);
  transpose_cast2h<<<dim3(GATE_D / 32, HID_D / 32), 256, 0, stream>>>(g1_w, g1_wT2, HID_D, GATE_D);

  // LN + tanh (sums 2 partials + bias) -> h2 ([A] reuse: obs2 dead)
  ln_tanh2h<<<T_DIM, 256, 0, stream>>>(hpP, trunk_b, h2, ln_g, ln_b);

  // p1: 2-way split-K partials ([C] reuse: hpP dead), then combine -> x2
  gemm_f16x2_sk<<<dim3(HID_D / 128, T_DIM / 128, 2), 256, 0, stream>>>(
      h2, p1_wT2, p1P, T_DIM, HID_D, FEAT_D);
  combine2_relu_split2h<<<(T_DIM * HID_D) / 1024, 256, 0, stream>>>(p1P, p1_b, x2);

  // gate1: 4-way split-K partials into hgP (h2 dead after p1)
  gemm_f16x2_sk<<<dim3(GATE_D / 128, T_DIM / 128, 4), 256, 0, stream>>>(
      x2, g1_wT2, hgP, T_DIM, GATE_D, HID_D);

  // gating pipeline — zero global atomics
  gate2_topk<<<NB_G, 256, 0, stream>>>(hgP, g1_b, g2_w, g2_b, blkimp, blkcnt, topi, topw, lrank);
  scan_k<<<1, 256, 0, stream>>>(blkcnt, counts, offsets, blkbase);
  fill_perm2<<<(T_DIM * TOPK) / 256, 256, 0, stream>>>(topi, lrank, blkbase, offsets, perm, inv);

  // expert value path (fp16, plane0 of x2), weights fp16
  transpose_casth<<<dim3(MH_D / 32, HID_D / 32, NE), 256, 0, stream>>>(ew1, ew1T, HID_D, MH_D);
  transpose_casth<<<dim3(HID_D / 32, MH_D / 32, NE), 256, 0, stream>>>(ew2, ew2T, MH_D, HID_D);
  expert_l1<<<dim3(MH_D / 128, 32, NE), 256, 0, stream>>>(
      x2, ew1T, eb1, perm, offsets, counts, hbuf);
  // ybuf overlays p1P (dead after combine)
  expert_l2<<<dim3(HID_D / 128, 32, NE), 256, 0, stream>>>(
      hbuf, ew2T, eb2, offsets, counts, ybuf);

  p2_head<<<T_DIM / 4, 256, 0, stream>>>(ybuf, inv, topw, p2_w, p2_b, stdp, out);
  aux_kernel<<<1, 256, 0, stream>>>(blkimp, counts, out);
}

// Round 10
// 268.394 us; speedup vs baseline: 1.7001x; 1.2171x over previous
//
#include <hip/hip_runtime.h>
#include <math.h>

#define T_DIM  4096
#define REPR_D 2048
#define FEAT_D 1024
#define HID_D  1024
#define GATE_D 256
#define MH_D   256
#define NE     32
#define TOPK   4
#define ACT_D  12
#define LN_EPS 1e-5f
#define NB_G   (T_DIM / 8)     // gate2 blocks (8 tokens each)

typedef unsigned short u16;
typedef __attribute__((ext_vector_type(8))) _Float16 f16x8;
typedef __attribute__((ext_vector_type(4))) float f32x4;
typedef __attribute__((ext_vector_type(4))) unsigned short u16x4;

__device__ __forceinline__ u16 f2h_bits(float f) {
  _Float16 h = (_Float16)f;
  return __builtin_bit_cast(u16, h);
}
__device__ __forceinline__ float h2f(u16 v) {
  return (float)__builtin_bit_cast(_Float16, v);
}
// split v = h0 + h1*2^-11, h1 stored pre-scaled by 2^11 (avoids fp16 subnormals)
__device__ __forceinline__ void split2h(float v, u16* h0, u16* h1) {
  _Float16 a = (_Float16)v;
  float r = v - (float)a;
  *h0 = __builtin_bit_cast(u16, a);
  *h1 = f2h_bits(r * 2048.0f);
}

__device__ __forceinline__ void gload16(const u16* g, u16* l) {
  __builtin_amdgcn_global_load_lds(
      (const __attribute__((address_space(1))) unsigned int*)g,
      (__attribute__((address_space(3))) unsigned int*)l, 16, 0, 0);
}

// ============ fp16x2 f32-emulated MFMA GEMM, 128x64 tile, BK=64, 48KB LDS ==============
// 3 blocks/CU residency (was 2 at 128x128/64KB). Slot-XOR LDS swizzle as before.
__global__ __launch_bounds__(256)
void gemm_f16x2_sk(const u16* __restrict__ A, const u16* __restrict__ Bt,
                   float* __restrict__ Cp, int M, int N, int K) {
  __shared__ u16 lA[2][128 * 64];   // 32 KB
  __shared__ u16 lB[2][64 * 64];    // 16 KB
  const int tid = threadIdx.x;
  // bijective XCD-chunk swizzle (requires nwg % 8 == 0; all launches satisfy)
  const unsigned gx = gridDim.x, gy = gridDim.y;
  const unsigned lin = blockIdx.x + gx * (blockIdx.y + gy * blockIdx.z);
  const unsigned q = (gx * gy * gridDim.z) >> 3;
  const unsigned swz = (lin & 7) * q + (lin >> 3);
  const int bn = (swz % gx) * 64;
  const int bm = ((swz / gx) % gy) * 128;
  const int bz = swz / (gx * gy);
  const int ksl = K / gridDim.z;
  const int kbeg = bz * ksl, kend = kbeg + ksl;
  const int lane = tid & 63, wid = tid >> 6;
  const int wm = (wid >> 1) * 64, wn = (wid & 1) * 32;
  const size_t sA = (size_t)M * K, sB = (size_t)N * K;
  const int srow = tid >> 3;                        // 0..31
  const int coff = ((tid & 7) ^ (srow & 7)) * 8;    // pre-swizzled source slot
  const u16* pa = A + (size_t)(bm + srow) * K + coff;
  const u16* pb = Bt + (size_t)(bn + srow) * K + coff;
  u16* la = &lA[0][0] + tid * 8;
  u16* lb = &lB[0][0] + tid * 8;
  const int fr = lane & 15, sx = lane >> 4, rx = lane & 7;
  f32x4 acc1[4][2] = {}, acc2[4][2] = {};
  for (int k0 = kbeg; k0 < kend; k0 += 64) {
    #pragma unroll
    for (int p = 0; p < 2; ++p) {
      #pragma unroll
      for (int s = 0; s < 4; ++s)
        gload16(pa + p * sA + (size_t)(s * 32) * K + k0, la + p * 8192 + s * 2048);
      #pragma unroll
      for (int s = 0; s < 2; ++s)
        gload16(pb + p * sB + (size_t)(s * 32) * K + k0, lb + p * 4096 + s * 2048);
    }
    __syncthreads();
    #pragma unroll
    for (int kh = 0; kh < 2; ++kh) {
      const int sa = (((kh << 2) | sx) ^ rx) * 8;
      f16x8 af0[4], af1[4], bq[2];
      #pragma unroll
      for (int m = 0; m < 4; ++m) {
        af0[m] = *(const f16x8*)&lA[0][(wm + m * 16 + fr) * 64 + sa];
        af1[m] = *(const f16x8*)&lA[1][(wm + m * 16 + fr) * 64 + sa];
      }
      #pragma unroll
      for (int n = 0; n < 2; ++n)
        bq[n] = *(const f16x8*)&lB[0][(wn + n * 16 + fr) * 64 + sa];
      #pragma unroll
      for (int m = 0; m < 4; ++m)
        #pragma unroll
        for (int n = 0; n < 2; ++n) {
          acc1[m][n] = __builtin_amdgcn_mfma_f32_16x16x32_f16(af0[m], bq[n], acc1[m][n], 0, 0, 0);
          acc2[m][n] = __builtin_amdgcn_mfma_f32_16x16x32_f16(af1[m], bq[n], acc2[m][n], 0, 0, 0);
        }
      #pragma unroll
      for (int n = 0; n < 2; ++n)
        bq[n] = *(const f16x8*)&lB[1][(wn + n * 16 + fr) * 64 + sa];
      #pragma unroll
      for (int m = 0; m < 4; ++m)
        #pragma unroll
        for (int n = 0; n < 2; ++n)
          acc2[m][n] = __builtin_amdgcn_mfma_f32_16x16x32_f16(af0[m], bq[n], acc2[m][n], 0, 0, 0);
    }
    __syncthreads();
  }
  float* Co = Cp + (size_t)bz * M * N;
  #pragma unroll
  for (int n = 0; n < 2; ++n) {
    const int col = bn + wn + n * 16 + (lane & 15);
    #pragma unroll
    for (int m = 0; m < 4; ++m) {
      #pragma unroll
      for (int r = 0; r < 4; ++r) {
        const int row = bm + wm + m * 16 + (lane >> 4) * 4 + r;
        Co[(size_t)row * N + col] = acc1[m][n][r] + acc2[m][n][r] * (1.0f / 2048.0f);
      }
    }
  }
}

// ============ expert layer 1: gathered-A fp16 MFMA, 128x64 tile, BK=64, 24KB LDS =======
__global__ __launch_bounds__(256)
void expert_l1(const u16* __restrict__ x, const u16* __restrict__ ew1T,
               const float* __restrict__ eb1, const int* __restrict__ perm,
               const int* __restrict__ offsets, const int* __restrict__ counts,
               u16* __restrict__ hbuf) {
  const int e = blockIdx.z;
  const int cnt = counts[e];
  const int r0 = blockIdx.y * 128;
  if (r0 >= cnt) return;
  const int base = offsets[e];
  const int bn = blockIdx.x * 64;
  __shared__ u16 lA[128 * 64];   // 16 KB
  __shared__ u16 lB[64 * 64];    // 8 KB
  __shared__ int toksm[128];
  const int tid = threadIdx.x;
  if (tid < 128) toksm[tid] = (r0 + tid < cnt) ? (perm[base + r0 + tid] >> 2) : 0;
  __syncthreads();
  const int lane = tid & 63, wid = tid >> 6;
  const int wm = (wid >> 1) * 64, wn = (wid & 1) * 32;
  const int srow = tid >> 3;
  const int coff = ((tid & 7) ^ (srow & 7)) * 8;
  const u16* pa[4]; const u16* pb[2];
  #pragma unroll
  for (int s = 0; s < 4; ++s)
    pa[s] = x + (size_t)toksm[srow + 32 * s] * HID_D + coff;
  #pragma unroll
  for (int s = 0; s < 2; ++s)
    pb[s] = ew1T + (size_t)e * MH_D * HID_D + (size_t)(bn + srow + 32 * s) * HID_D + coff;
  u16* la = lA + tid * 8;
  u16* lb = lB + tid * 8;
  const int fr = lane & 15, sx = lane >> 4, rx = lane & 7;
  f32x4 acc[4][2] = {};
  for (int k0 = 0; k0 < HID_D; k0 += 64) {
    #pragma unroll
    for (int s = 0; s < 4; ++s) gload16(pa[s] + k0, la + s * 2048);
    #pragma unroll
    for (int s = 0; s < 2; ++s) gload16(pb[s] + k0, lb + s * 2048);
    __syncthreads();
    #pragma unroll
    for (int kh = 0; kh < 2; ++kh) {
      const int sa = (((kh << 2) | sx) ^ rx) * 8;
      f16x8 af[4], bq[2];
      #pragma unroll
      for (int m = 0; m < 4; ++m)
        af[m] = *(const f16x8*)&lA[(wm + m * 16 + fr) * 64 + sa];
      #pragma unroll
      for (int n = 0; n < 2; ++n)
        bq[n] = *(const f16x8*)&lB[(wn + n * 16 + fr) * 64 + sa];
      #pragma unroll
      for (int m = 0; m < 4; ++m)
        #pragma unroll
        for (int n = 0; n < 2; ++n)
          acc[m][n] = __builtin_amdgcn_mfma_f32_16x16x32_f16(af[m], bq[n], acc[m][n], 0, 0, 0);
    }
    __syncthreads();
  }
  #pragma unroll
  for (int n = 0; n < 2; ++n) {
    const int col = bn + wn + n * 16 + (lane & 15);
    const float bz = eb1[e * MH_D + col];
    #pragma unroll
    for (int m = 0; m < 4; ++m) {
      #pragma unroll
      for (int r = 0; r < 4; ++r) {
        const int rl = wm + m * 16 + (lane >> 4) * 4 + r;
        if (r0 + rl < cnt) {
          const float v = fmaxf(acc[m][n][r] + bz, 0.f);
          hbuf[(size_t)(base + r0 + rl) * MH_D + col] = f2h_bits(v);
        }
      }
    }
  }
}

// ============ expert layer 2: fp16 MFMA, 128x64 tile, BK=64, 24KB LDS ==================
__global__ __launch_bounds__(256)
void expert_l2(const u16* __restrict__ hbuf, const u16* __restrict__ ew2T,
               const float* __restrict__ eb2, const int* __restrict__ offsets,
               const int* __restrict__ counts, u16* __restrict__ ybuf) {
  const int e = blockIdx.z;
  const int cnt = counts[e];
  const int r0 = blockIdx.y * 128;
  if (r0 >= cnt) return;
  const int base = offsets[e];
  const int bn = blockIdx.x * 64;
  __shared__ u16 lA[128 * 64];
  __shared__ u16 lB[64 * 64];
  const int tid = threadIdx.x;
  const int lane = tid & 63, wid = tid >> 6;
  const int wm = (wid >> 1) * 64, wn = (wid & 1) * 32;
  const int srow = tid >> 3;
  const int coff = ((tid & 7) ^ (srow & 7)) * 8;
  const u16* pa[4]; const u16* pb[2];
  #pragma unroll
  for (int s = 0; s < 4; ++s) {
    const int rr = r0 + srow + 32 * s;
    const int rc = (rr < cnt) ? rr : cnt - 1;
    pa[s] = hbuf + (size_t)(base + rc) * MH_D + coff;
  }
  #pragma unroll
  for (int s = 0; s < 2; ++s)
    pb[s] = ew2T + (size_t)e * HID_D * MH_D + (size_t)(bn + srow + 32 * s) * MH_D + coff;
  u16* la = lA + tid * 8;
  u16* lb = lB + tid * 8;
  const int fr = lane & 15, sx = lane >> 4, rx = lane & 7;
  f32x4 acc[4][2] = {};
  for (int k0 = 0; k0 < MH_D; k0 += 64) {
    #pragma unroll
    for (int s = 0; s < 4; ++s) gload16(pa[s] + k0, la + s * 2048);
    #pragma unroll
    for (int s = 0; s < 2; ++s) gload16(pb[s] + k0, lb + s * 2048);
    __syncthreads();
    #pragma unroll
    for (int kh = 0; kh < 2; ++kh) {
      const int sa = (((kh << 2) | sx) ^ rx) * 8;
      f16x8 af[4], bq[2];
      #pragma unroll
      for (int m = 0; m < 4; ++m)
        af[m] = *(const f16x8*)&lA[(wm + m * 16 + fr) * 64 + sa];
      #pragma unroll
      for (int n = 0; n < 2; ++n)
        bq[n] = *(const f16x8*)&lB[(wn + n * 16 + fr) * 64 + sa];
      #pragma unroll
      for (int m = 0; m < 4; ++m)
        #pragma unroll
        for (int n = 0; n < 2; ++n)
          acc[m][n] = __builtin_amdgcn_mfma_f32_16x16x32_f16(af[m], bq[n], acc[m][n], 0, 0, 0);
    }
    __syncthreads();
  }
  #pragma unroll
  for (int n = 0; n < 2; ++n) {
    const int col = bn + wn + n * 16 + (lane & 15);
    const float bz = eb2[e * HID_D + col];
    #pragma unroll
    for (int m = 0; m < 4; ++m) {
      #pragma unroll
      for (int r = 0; r < 4; ++r) {
        const int rl = wm + m * 16 + (lane >> 4) * 4 + r;
        if (r0 + rl < cnt)
          ybuf[(size_t)(base + r0 + rl) * HID_D + col] = f2h_bits(acc[m][n][r] + bz);
      }
    }
  }
}

// ============ cast / transpose / split helpers ==========================================
__global__ __launch_bounds__(256)
void cast2h_k(const float* __restrict__ in, u16* __restrict__ out, size_t total) {
  const size_t i = ((size_t)blockIdx.x * 256 + threadIdx.x) * 4;
  const float4 v = *(const float4*)(in + i);
  const float vv[4] = {v.x, v.y, v.z, v.w};
  u16x4 o0, o1;
  #pragma unroll
  for (int j = 0; j < 4; ++j) {
    u16 a, b;
    split2h(vv[j], &a, &b);
    o0[j] = a; o1[j] = b;
  }
  *(u16x4*)(out + i) = o0;
  *(u16x4*)(out + total + i) = o1;
}

// in: f32 [K][N], out: 2 fp16 planes [N][K]
__global__ __launch_bounds__(256)
void transpose_cast2h(const float* __restrict__ in, u16* __restrict__ out, int K, int N) {
  __shared__ float t[32][33];
  const int bn = blockIdx.x * 32, bk = blockIdx.y * 32;
  const int tx = threadIdx.x & 31, ty = threadIdx.x >> 5;
  const size_t NK = (size_t)N * K;
  #pragma unroll
  for (int i = 0; i < 32; i += 8) t[ty + i][tx] = in[(size_t)(bk + ty + i) * N + bn + tx];
  __syncthreads();
  #pragma unroll
  for (int i = 0; i < 32; i += 8) {
    const size_t idx = (size_t)(bn + ty + i) * K + bk + tx;
    u16 h0, h1;
    split2h(t[tx][ty + i], &h0, &h1);
    out[idx] = h0; out[idx + NK] = h1;
  }
}

// single-plane fp16 transpose-cast (expert weights)
__global__ __launch_bounds__(256)
void transpose_casth(const float* __restrict__ in, u16* __restrict__ out, int K, int N) {
  const size_t off = (size_t)blockIdx.z * K * N;
  in += off; out += off;
  __shared__ float t[32][33];
  const int bn = blockIdx.x * 32, bk = blockIdx.y * 32;
  const int tx = threadIdx.x & 31, ty = threadIdx.x >> 5;
  #pragma unroll
  for (int i = 0; i < 32; i += 8) t[ty + i][tx] = in[(size_t)(bk + ty + i) * N + bn + tx];
  __syncthreads();
  #pragma unroll
  for (int i = 0; i < 32; i += 8) out[(size_t)(bn + ty + i) * K + bk + tx] = f2h_bits(t[tx][ty + i]);
}

// ============ LN + tanh: sums 2 trunk partials + bias -> 2 fp16 planes ==================
__global__ __launch_bounds__(256)
void ln_tanh2h(const float* __restrict__ hp, const float* __restrict__ tb,
               u16* __restrict__ outp, const float* __restrict__ g,
               const float* __restrict__ b) {
  const int row = blockIdx.x, tid = threadIdx.x;
  const size_t MN = (size_t)T_DIM * FEAT_D;
  const float4 va = ((const float4*)(hp + (size_t)row * FEAT_D))[tid];
  const float4 vb = ((const float4*)(hp + MN + (size_t)row * FEAT_D))[tid];
  const float4 vt = ((const float4*)tb)[tid];
  float4 v;
  v.x = va.x + vb.x + vt.x; v.y = va.y + vb.y + vt.y;
  v.z = va.z + vb.z + vt.z; v.w = va.w + vb.w + vt.w;
  float s = v.x + v.y + v.z + v.w;
  float ss = v.x * v.x + v.y * v.y + v.z * v.z + v.w * v.w;
  #pragma unroll
  for (int d = 32; d >= 1; d >>= 1) { s += __shfl_xor(s, d, 64); ss += __shfl_xor(ss, d, 64); }
  __shared__ float red[2][4];
  const int w = tid >> 6;
  if ((tid & 63) == 0) { red[0][w] = s; red[1][w] = ss; }
  __syncthreads();
  s  = red[0][0] + red[0][1] + red[0][2] + red[0][3];
  ss = red[1][0] + red[1][1] + red[1][2] + red[1][3];
  const float m = s * (1.f / FEAT_D);
  const float inv = rsqrtf(ss * (1.f / FEAT_D) - m * m + LN_EPS);
  const float4 gg = ((const float4*)g)[tid];
  const float4 bb = ((const float4*)b)[tid];
  const float tv[4] = {tanhf((v.x - m) * inv * gg.x + bb.x),
                       tanhf((v.y - m) * inv * gg.y + bb.y),
                       tanhf((v.z - m) * inv * gg.z + bb.z),
                       tanhf((v.w - m) * inv * gg.w + bb.w)};
  u16x4 o0, o1;
  #pragma unroll
  for (int j = 0; j < 4; ++j) {
    u16 a, c;
    split2h(tv[j], &a, &c);
    o0[j] = a; o1[j] = c;
  }
  ((u16x4*)(outp + (size_t)row * FEAT_D))[tid] = o0;
  ((u16x4*)(outp + MN + (size_t)row * FEAT_D))[tid] = o1;
}

// ============ p1 combiner: sum 2 partials + bias, relu, split2 ==========================
__global__ __launch_bounds__(256)
void combine2_relu_split2h(const float* __restrict__ P, const float* __restrict__ bias,
                           u16* __restrict__ out2) {
  const size_t MN = (size_t)T_DIM * HID_D;
  const size_t i = ((size_t)blockIdx.x * 256 + threadIdx.x) * 4;
  const float4 a = *(const float4*)(P + i);
  const float4 b = *(const float4*)(P + MN + i);
  const float4 bz = *(const float4*)(bias + (i & (HID_D - 1)));
  const float vv[4] = {fmaxf(a.x + b.x + bz.x, 0.f), fmaxf(a.y + b.y + bz.y, 0.f),
                       fmaxf(a.z + b.z + bz.z, 0.f), fmaxf(a.w + b.w + bz.w, 0.f)};
  u16x4 o0, o1;
  #pragma unroll
  for (int j = 0; j < 4; ++j) {
    u16 h0, h1;
    split2h(vv[j], &h0, &h1);
    o0[j] = h0; o1[j] = h1;
  }
  *(u16x4*)(out2 + i) = o0;
  *(u16x4*)(out2 + MN + i) = o1;
}

// ============ gate2: logits + softmax + top-4 + per-block partials (NO global atomics) ==
__global__ __launch_bounds__(256)
void gate2_topk(const float* __restrict__ hgP, const float* __restrict__ g1b,
                const float* __restrict__ g2w, const float* __restrict__ g2b,
                float* __restrict__ blkimp, int* __restrict__ blkcnt,
                int* __restrict__ topi, float* __restrict__ topw,
                int* __restrict__ lrank) {
  __shared__ float wsm[GATE_D][NE];
  __shared__ float rows[8][GATE_D];
  __shared__ float pacc[8][NE];
  __shared__ int lhist[NE];
  const int tid = threadIdx.x;
  const int t0 = blockIdx.x * 8;
  const size_t TG = (size_t)T_DIM * GATE_D;
  if (tid < NE) lhist[tid] = 0;
  {
    float4* wv = (float4*)&wsm[0][0];
    const float4* gv = (const float4*)g2w;
    #pragma unroll
    for (int i = 0; i < 8; ++i) wv[tid + 256 * i] = gv[tid + 256 * i];
  }
  {
    const float4* p0 = (const float4*)hgP;
    const float4* p1 = (const float4*)(hgP + TG);
    const float4* p2 = (const float4*)(hgP + 2 * TG);
    const float4* p3 = (const float4*)(hgP + 3 * TG);
    const float4* bv = (const float4*)g1b;
    float4* rv = (float4*)&rows[0][0];
    #pragma unroll
    for (int i = 0; i < 2; ++i) {
      const int idx = tid + 256 * i;
      const int r = idx >> 6, c4 = idx & 63;
      const size_t gidx = (size_t)(t0 + r) * (GATE_D / 4) + c4;
      const float4 a = p0[gidx], b = p1[gidx], c = p2[gidx], d = p3[gidx];
      const float4 bb = bv[c4];
      float4 v;
      v.x = fmaxf(a.x + b.x + c.x + d.x + bb.x, 0.f);
      v.y = fmaxf(a.y + b.y + c.y + d.y + bb.y, 0.f);
      v.z = fmaxf(a.z + b.z + c.z + d.z + bb.z, 0.f);
      v.w = fmaxf(a.w + b.w + c.w + d.w + bb.w, 0.f);
      rv[idx] = v;
    }
  }
  __syncthreads();
  const int tl = tid >> 5;
  const int e  = tid & 31;
  const int t  = t0 + tl;
  float a8[8] = {};
  #pragma unroll
  for (int k0 = 0; k0 < GATE_D; k0 += 8)
    #pragma unroll
    for (int j = 0; j < 8; ++j)
      a8[j] = fmaf(rows[tl][k0 + j], wsm[k0 + j][e], a8[j]);
  const float logit = g2b[e] +
      (((a8[0] + a8[1]) + (a8[2] + a8[3])) + ((a8[4] + a8[5]) + (a8[6] + a8[7])));
  float m = logit;
  #pragma unroll
  for (int d = 16; d >= 1; d >>= 1) m = fmaxf(m, __shfl_xor(m, d, 32));
  const float p = expf(logit - m);
  float ssum = p;
  #pragma unroll
  for (int d = 16; d >= 1; d >>= 1) ssum += __shfl_xor(ssum, d, 32);
  const float prob = p / ssum;
  pacc[tl][e] = prob;
  __syncthreads();
  if (tl == 0) {
    float a = 0.f;
    #pragma unroll
    for (int q = 0; q < 8; ++q) a += pacc[q][e];
    blkimp[blockIdx.x * NE + e] = a;
  }
  float cur = prob;
  float wv[TOPK]; int wi[TOPK];
  #pragma unroll
  for (int it = 0; it < TOPK; ++it) {
    float v = cur; int idx = e;
    #pragma unroll
    for (int d = 16; d >= 1; d >>= 1) {
      float v2 = __shfl_xor(v, d, 32);
      int   i2 = __shfl_xor(idx, d, 32);
      if (v2 > v || (v2 == v && i2 < idx)) { v = v2; idx = i2; }
    }
    wv[it] = v; wi[it] = idx;
    if (e == idx) cur = -1e30f;
  }
  if (e == 0) {
    const float s4 = wv[0] + wv[1] + wv[2] + wv[3];
    #pragma unroll
    for (int k2 = 0; k2 < TOPK; ++k2) {
      topi[t * TOPK + k2] = wi[k2];
      topw[t * TOPK + k2] = wv[k2] / s4;
      lrank[t * TOPK + k2] = atomicAdd(&lhist[wi[k2]], 1);   // LDS atomic (per-CU, fast)
    }
  }
  __syncthreads();
  if (tid < NE) blkcnt[blockIdx.x * NE + tid] = lhist[tid];
}

// ============ scan: blkcnt -> counts, offsets, per-block bases (1 block) ================
__global__ __launch_bounds__(256)
void scan_k(const int* __restrict__ blkcnt, int* __restrict__ counts,
            int* __restrict__ offsets, int* __restrict__ blkbase) {
  __shared__ int segsum[8][NE];
  __shared__ int soff[8][NE];
  const int e = threadIdx.x & 31, seg = threadIdx.x >> 5;    // 8 segs x 64 blocks
  const int b0 = seg * 64;
  int vals[64];
  #pragma unroll
  for (int i = 0; i < 64; ++i) vals[i] = blkcnt[(b0 + i) * NE + e];
  int run = 0;
  #pragma unroll
  for (int i = 0; i < 64; ++i) { const int c = vals[i]; vals[i] = run; run += c; }
  segsum[seg][e] = run;
  __syncthreads();
  if (seg == 0) {
    int acc = 0;
    #pragma unroll
    for (int s2 = 0; s2 < 8; ++s2) { soff[s2][e] = acc; acc += segsum[s2][e]; }
    counts[e] = acc;
  }
  __syncthreads();
  if (threadIdx.x == 0) {
    int a = 0;
    for (int i = 0; i < NE; ++i) { offsets[i] = a; a += counts[i]; }
    offsets[NE] = a;
  }
  const int sb = soff[seg][e];
  #pragma unroll
  for (int i = 0; i < 64; ++i) blkbase[(b0 + i) * NE + e] = sb + vals[i];
}

// ============ fill_perm2: position = offsets + blkbase + lrank (NO atomics) =============
__global__ __launch_bounds__(256)
void fill_perm2(const int* __restrict__ topi, const int* __restrict__ lrank,
                const int* __restrict__ blkbase, const int* __restrict__ offsets,
                int* __restrict__ perm, int* __restrict__ inv) {
  const int s = blockIdx.x * 256 + threadIdx.x;
  const int e = topi[s];
  const int b = s >> 5;                       // 32 slots per gate2 block
  const int pos = offsets[e] + blkbase[b * NE + e] + lrank[s];
  perm[pos] = s;
  inv[s] = pos;
}

// ============ p2 head: gather 4 ybuf rows, combine, relu, GEMV, tanh; std ==============
__global__ __launch_bounds__(256)
void p2_head(const u16* __restrict__ ybuf, const int* __restrict__ inv,
             const float* __restrict__ topw, const float* __restrict__ w,
             const float* __restrict__ b, const float* __restrict__ stdp,
             float* __restrict__ outp) {
  const int t = (blockIdx.x * 256 + threadIdx.x) >> 6;
  const int lane = threadIdx.x & 63;
  if (t >= T_DIM) return;
  const int p0 = inv[t * 4 + 0], p1 = inv[t * 4 + 1];
  const int p2 = inv[t * 4 + 2], p3 = inv[t * 4 + 3];
  const float w0 = topw[t * 4 + 0], w1 = topw[t * 4 + 1];
  const float w2 = topw[t * 4 + 2], w3 = topw[t * 4 + 3];
  const u16* y0 = ybuf + (size_t)p0 * HID_D;
  const u16* y1 = ybuf + (size_t)p1 * HID_D;
  const u16* y2 = ybuf + (size_t)p2 * HID_D;
  const u16* y3 = ybuf + (size_t)p3 * HID_D;
  float a[ACT_D] = {};
  for (int k = lane; k < HID_D; k += 64) {
    float xv = w0 * h2f(y0[k]) + w1 * h2f(y1[k]) + w2 * h2f(y2[k]) + w3 * h2f(y3[k]);
    xv = fmaxf(xv, 0.f);
    const float* wr = w + (size_t)k * ACT_D;
    #pragma unroll
    for (int j = 0; j < ACT_D; ++j) a[j] = fmaf(xv, wr[j], a[j]);
  }
  #pragma unroll
  for (int j = 0; j < ACT_D; ++j) {
    float v = a[j];
    #pragma unroll
    for (int d = 32; d >= 1; d >>= 1) v += __shfl_xor(v, d, 64);
    a[j] = v;
  }
  if (lane == 0) {
    const float sv = stdp[0];
    #pragma unroll
    for (int j = 0; j < ACT_D; ++j) {
      outp[(size_t)t * ACT_D + j] = tanhf(a[j] + b[j]);
      outp[(size_t)T_DIM * ACT_D + (size_t)t * ACT_D + j] = sv;
    }
  }
}

// ============ aux: reduce blkimp deterministically + counts -> aux loss ================
__global__ __launch_bounds__(256)
void aux_kernel(const float* __restrict__ blkimp, const int* __restrict__ counts,
                float* __restrict__ outp) {
  __shared__ float part[8][NE];
  const int e = threadIdx.x & 31, seg = threadIdx.x >> 5;
  float a = 0.f;
  #pragma unroll
  for (int i = 0; i < 64; ++i) a += blkimp[((seg << 6) + i) * NE + e];
  part[seg][e] = a;
  __syncthreads();
  if (threadIdx.x < 32) {
    float impe = 0.f;
    #pragma unroll
    for (int s2 = 0; s2 < 8; ++s2) impe += part[s2][e];
    float v = (impe / (float)T_DIM) * ((float)counts[e] / (float)(T_DIM * TOPK));
    #pragma unroll
    for (int d = 16; d >= 1; d >>= 1) v += __shfl_xor(v, d, 32);
    if (e == 0) outp[2 * T_DIM * ACT_D] = (float)NE * v;
  }
}

extern "C" void kernel_launch(void* const* d_in, const int* in_sizes, int n_in,
                              void* d_out, int out_size, void* d_ws, size_t ws_size,
                              hipStream_t stream) {
  const float* obs     = (const float*)d_in[0];
  const float* stdp    = (const float*)d_in[1];
  const float* trunk_w = (const float*)d_in[2];
  const float* trunk_b = (const float*)d_in[3];
  const float* ln_g    = (const float*)d_in[4];
  const float* ln_b    = (const float*)d_in[5];
  const float* p1_w    = (const float*)d_in[6];
  const float* p1_b    = (const float*)d_in[7];
  const float* g1_w    = (const float*)d_in[8];
  const float* g1_b    = (const float*)d_in[9];
  const float* g2_w    = (const float*)d_in[10];
  const float* g2_b    = (const float*)d_in[11];
  const float* ew1     = (const float*)d_in[12];
  const float* eb1     = (const float*)d_in[13];
  const float* ew2     = (const float*)d_in[14];
  const float* eb2     = (const float*)d_in[15];
  const float* p2_w    = (const float*)d_in[16];
  const float* p2_b    = (const float*)d_in[17];
  float* out = (float*)d_out;

  // ---- workspace layout with lifetime overlays ----
  char* p = (char*)d_ws;
  // [A] 33.55 MB: obs2 -> {h2 16.78 | x2 16.78}; h2 -> hgP (4xTxGATE f32) after p1
  u16*   obs2 = (u16*)p;
  u16*   h2   = (u16*)p;
  float* hgP  = (float*)p;
  u16*   x2   = (u16*)(p + 2 * (size_t)T_DIM * FEAT_D * 2);
  p += 2 * (size_t)T_DIM * REPR_D * 2;
  // [B] 8.39 MB: trunk_wT2 -> {p1_wT2 4.19 + g1_wT2 1.05} -> hbuf 8.39
  u16* trunk_wT2 = (u16*)p;
  u16* p1_wT2    = (u16*)p;
  u16* g1_wT2    = (u16*)(p + 2 * (size_t)FEAT_D * HID_D * 2);
  u16* hbuf      = (u16*)p;
  p += 2 * (size_t)REPR_D * FEAT_D * 2;
  // [C] 33.55 MB: trunk partials (2 f32 planes) -> p1 partials -> ybuf (fp16, 16384x1024)
  float* hpP  = (float*)p;
  float* p1P  = (float*)p;
  u16*   ybuf = (u16*)p;
  p += 2 * (size_t)T_DIM * FEAT_D * 4;
  u16* ew1T = (u16*)p; p += (size_t)NE * HID_D * MH_D * 2;   // 16.78 MB
  u16* ew2T = (u16*)p; p += (size_t)NE * HID_D * MH_D * 2;   // 16.78 MB
  float* topw    = (float*)p; p += (size_t)T_DIM * TOPK * 4;
  int*   topi    = (int*)p;   p += (size_t)T_DIM * TOPK * 4;
  int*   perm    = (int*)p;   p += (size_t)T_DIM * TOPK * 4;
  int*   inv     = (int*)p;   p += (size_t)T_DIM * TOPK * 4;
  int*   lrank   = (int*)p;   p += (size_t)T_DIM * TOPK * 4;
  float* blkimp  = (float*)p; p += (size_t)NB_G * NE * 4;
  int*   blkcnt  = (int*)p;   p += (size_t)NB_G * NE * 4;
  int*   blkbase = (int*)p;   p += (size_t)NB_G * NE * 4;
  int*   counts  = (int*)p;   p += 128;
  int*   offsets = (int*)p;   p += 256;

  // obs + trunk_w -> 2-plane fp16 splits
  cast2h_k<<<(T_DIM * REPR_D) / 1024, 256, 0, stream>>>(obs, obs2, (size_t)T_DIM * REPR_D);
  transpose_cast2h<<<dim3(FEAT_D / 32, REPR_D / 32), 256, 0, stream>>>(trunk_w, trunk_wT2, REPR_D, FEAT_D);

  // trunk: 2-way split-K partials (1024 blocks, XCD-chunked, 128x64 tiles)
  gemm_f16x2_sk<<<dim3(FEAT_D / 64, T_DIM / 128, 2), 256, 0, stream>>>(
      obs2, trunk_wT2, hpP, T_DIM, FEAT_D, REPR_D);
  // [B] reuse (trunk_wT2 dead)
  transpose_cast2h<<<dim3(HID_D / 32, FEAT_D / 32), 256, 0, stream>>>(p1_w, p1_wT2, FEAT_D, HID_D);
  transpose_cast2h<<<dim3(GATE_D / 32, HID_D / 32), 256, 0, stream>>>(g1_w, g1_wT2, HID_D, GATE_D);

  // LN + tanh (sums 2 partials + bias) -> h2 ([A] reuse: obs2 dead)
  ln_tanh2h<<<T_DIM, 256, 0, stream>>>(hpP, trunk_b, h2, ln_g, ln_b);

  // p1: 2-way split-K partials ([C] reuse: hpP dead), then combine -> x2
  gemm_f16x2_sk<<<dim3(HID_D / 64, T_DIM / 128, 2), 256, 0, stream>>>(
      h2, p1_wT2, p1P, T_DIM, HID_D, FEAT_D);
  combine2_relu_split2h<<<(T_DIM * HID_D) / 1024, 256, 0, stream>>>(p1P, p1_b, x2);

  // gate1: 4-way split-K partials into hgP (h2 dead after p1)
  gemm_f16x2_sk<<<dim3(GATE_D / 64, T_DIM / 128, 4), 256, 0, stream>>>(
      x2, g1_wT2, hgP, T_DIM, GATE_D, HID_D);

  // gating pipeline — zero global atomics
  gate2_topk<<<NB_G, 256, 0, stream>>>(hgP, g1_b, g2_w, g2_b, blkimp, blkcnt, topi, topw, lrank);
  scan_k<<<1, 256, 0, stream>>>(blkcnt, counts, offsets, blkbase);
  fill_perm2<<<(T_DIM * TOPK) / 256, 256, 0, stream>>>(topi, lrank, blkbase, offsets, perm, inv);

  // expert value path (fp16, plane0 of x2), weights fp16
  transpose_casth<<<dim3(MH_D / 32, HID_D / 32, NE), 256, 0, stream>>>(ew1, ew1T, HID_D, MH_D);
  transpose_casth<<<dim3(HID_D / 32, MH_D / 32, NE), 256, 0, stream>>>(ew2, ew2T, MH_D, HID_D);
  expert_l1<<<dim3(MH_D / 64, 32, NE), 256, 0, stream>>>(
      x2, ew1T, eb1, perm, offsets, counts, hbuf);
  // ybuf overlays p1P (dead after combine)
  expert_l2<<<dim3(HID_D / 64, 32, NE), 256, 0, stream>>>(
      hbuf, ew2T, eb2, offsets, counts, ybuf);

  p2_head<<<T_DIM / 4, 256, 0, stream>>>(ybuf, inv, topw, p2_w, p2_b, stdp, out);
  aux_kernel<<<1, 256, 0, stream>>>(blkimp, counts, out);
}